// Round 7
// baseline (5234.122 us; speedup 1.0000x reference)
//
#include <hip/hip_runtime.h>
#include <hip/hip_bf16.h>

// SeqDecoderRNN: 2-layer GRU decoder, B=64 H=1024 C=128 T=256.
// Persistent cooperative kernel: 256 blocks x 256 threads, weights LDS-resident.
// Groups of 64 blocks: G0=gi0(+h0 elementwise), G1=gh0 (+y GEMM on 8 blocks),
// G2=gi1(+h1 elementwise), G3=gh1.
// Sync: WAVE-GRANULAR generation flags [group][wv][lid] — every dependency is
// wave_wv -> wave_wv, so waves pipeline independently (no __syncthreads in loop).
// All cross-block data via relaxed agent-scope atomics (LLC-direct).
// h mirrors frag-major (wave-contiguous 1KB fragments); gh handoff SoA u64
// [lid][comp][wv][lane] -> every instruction covers 512B contiguous.
// sched_barrier(0) fences pin program order around sync (rule #18 — load-bearing).

typedef __bf16 bf16_t;
typedef __bf16 bf8 __attribute__((ext_vector_type(8)));
typedef float  f4  __attribute__((ext_vector_type(4)));
typedef float  f2  __attribute__((ext_vector_type(2)));
typedef unsigned long long u64;
typedef u64 u64x2 __attribute__((ext_vector_type(2)));

static constexpr unsigned O_FLAGS = 0;                    // 256 u32 heavy-barrier flags
static constexpr unsigned O_FLG   = 1024;                 // 4 grp x 4 wv x 64 lid u32 = 4KB
static constexpr unsigned O_B0F   = 8192;                 // 3072 f32
static constexpr unsigned O_X0    = O_B0F + 12288;        // 64x128 bf16 (frag-major)
static constexpr unsigned O_H0B   = O_X0  + 16384;        // 64x1024 bf16 (frag-major)
static constexpr unsigned O_H1B   = O_H0B + 131072;       // 2 x 64x1024 bf16 ring (frag-major)
static constexpr unsigned O_GH0   = O_H1B + 262144;       // 64*6*4*64 u64 SoA
static constexpr unsigned O_GH1   = O_GH0 + 786432;       // 64*6*4*64 u64 SoA
static constexpr unsigned O_W0F   = O_GH1 + 786432;       // 3072x1024 bf16 (W_ih0 @ fc_W)

#define LDS_EXTRA 98304
#define LDS_SIZE  131072

__device__ __forceinline__ void sfence() { __builtin_amdgcn_sched_barrier(0); }

__device__ __forceinline__ float sigmoidf_(float x) { return 1.f / (1.f + __expf(-x)); }
__device__ __forceinline__ float tanhf_(float x) {
  float e = __expf(-2.f * fabsf(x));
  float t = (1.f - e) / (1.f + e);
  return x < 0.f ? -t : t;
}

// ---- LLC-direct (agent-scope relaxed atomic) access helpers ----
__device__ __forceinline__ u64 llc_ld64(const void* p) {
  return __hip_atomic_load((u64*)p, __ATOMIC_RELAXED, __HIP_MEMORY_SCOPE_AGENT);
}
__device__ __forceinline__ unsigned llc_ld32(const unsigned* p) {
  return __hip_atomic_load((unsigned*)p, __ATOMIC_RELAXED, __HIP_MEMORY_SCOPE_AGENT);
}
__device__ __forceinline__ void llc_st32(unsigned* p, unsigned v) {
  __hip_atomic_store(p, v, __ATOMIC_RELAXED, __HIP_MEMORY_SCOPE_AGENT);
}
__device__ __forceinline__ void llc_st64(u64* p, u64 v) {
  __hip_atomic_store(p, v, __ATOMIC_RELAXED, __HIP_MEMORY_SCOPE_AGENT);
}

// frag-major element index for a 64 x (NKS*32) matrix:
//   f(row,col) = ((row>>4)*NKS + (col>>5))*512 + (((col>>3)&3)*16 + (row&15))*8 + (col&7)

// 3-tile (r,z,n gates) GEMM: 16 rows x 48 cols per wave, K = NKS*32.
// A: frag-major bf16, LLC-direct, full prefetch. B: LDS XOR-swizzled, dbuf regs.
template<int NKS, int RS>
__device__ __forceinline__ void gemm3(const bf16_t* __restrict__ Afm,
                                      const char* lds, int lane, int rt,
                                      f4& c0, f4& c1, f4& c2)
{
  const int lo = lane & 15, hi = lane >> 4;
  const bf16_t* ap = Afm + (size_t)rt * (NKS * 512) + lane * 8;
  const int sw = lo & 7;
  const char* l0 = lds + lo * RS;
  const char* l1 = lds + (16 + lo) * RS;
  const char* l2 = lds + (32 + lo) * RS;
  u64 a0[NKS], a1[NKS];
#pragma unroll
  for (int p = 0; p < NKS; ++p) {
    a0[p] = llc_ld64(ap + p * 512);
    a1[p] = llc_ld64(ap + p * 512 + 4);
  }
  int xo0 = (hi ^ sw) * 16;
  bf8 b0 = *(const bf8*)(l0 + xo0);
  bf8 b1 = *(const bf8*)(l1 + xo0);
  bf8 b2 = *(const bf8*)(l2 + xo0);
#pragma unroll
  for (int ks = 0; ks < NKS; ++ks) {
    bf8 nb0, nb1, nb2;
    if (ks + 1 < NKS) {
      const int nxo = (((ks + 1) * 4 + hi) ^ sw) * 16;
      nb0 = *(const bf8*)(l0 + nxo);
      nb1 = *(const bf8*)(l1 + nxo);
      nb2 = *(const bf8*)(l2 + nxo);
    }
    u64x2 tt; tt.x = a0[ks]; tt.y = a1[ks];
    bf8 a = __builtin_bit_cast(bf8, tt);
    c0 = __builtin_amdgcn_mfma_f32_16x16x32_bf16(a, b0, c0, 0, 0, 0);
    c1 = __builtin_amdgcn_mfma_f32_16x16x32_bf16(a, b1, c1, 0, 0, 0);
    c2 = __builtin_amdgcn_mfma_f32_16x16x32_bf16(a, b2, c2, 0, 0, 0);
    b0 = nb0; b1 = nb1; b2 = nb2;
  }
}

// single-tile GEMM (y = h1 @ fcW^T slice): 16 rows x 16 cols per wave, K=1024.
__device__ __forceinline__ f4 gemm1(const bf16_t* __restrict__ Afm,
                                    const char* lds, int lane, int rt)
{
  const int lo = lane & 15, hi = lane >> 4;
  const bf16_t* ap = Afm + (size_t)rt * 16384 + lane * 8;
  const int sw = lo & 7;
  const char* lb = lds + lo * 2048;
  f4 acc = {0.f, 0.f, 0.f, 0.f};
  u64 a0[32], a1[32];
#pragma unroll
  for (int p = 0; p < 32; ++p) {
    a0[p] = llc_ld64(ap + p * 512);
    a1[p] = llc_ld64(ap + p * 512 + 4);
  }
  bf8 b = *(const bf8*)(lb + (hi ^ sw) * 16);
#pragma unroll
  for (int ks = 0; ks < 32; ++ks) {
    bf8 nb;
    if (ks + 1 < 32) nb = *(const bf8*)(lb + ((((ks + 1) * 4 + hi) ^ sw) * 16));
    u64x2 tt; tt.x = a0[ks]; tt.y = a1[ks];
    bf8 a = __builtin_bit_cast(bf8, tt);
    acc = __builtin_amdgcn_mfma_f32_16x16x32_bf16(a, b, acc, 0, 0, 0);
    b = nb;
  }
  return acc;
}

// gh handoff: SoA u64, index ((lid*6 + comp)*4 + wv)*64 + lane.
// Lane stride 8B -> each instruction covers 512B contiguous (no write amp).
// Producer thread (wv,lane) and consumer thread (wv,lane) hold identical elems.
__device__ __forceinline__ u64 pk2(float x, float y) {
  f2 v = {x, y}; return __builtin_bit_cast(u64, v);
}
__device__ __forceinline__ void gh_store_soa(u64* g, int lid, int wv, int lane,
                                             f4 c0, f4 c1, f4 c2,
                                             float br, float bz, float bn)
{
  u64* p = g + ((size_t)lid * 24 + wv) * 64 + lane;
  llc_st64(p,        pk2(c0[0] + br, c0[1] + br));
  llc_st64(p + 256,  pk2(c0[2] + br, c0[3] + br));
  llc_st64(p + 512,  pk2(c1[0] + bz, c1[1] + bz));
  llc_st64(p + 768,  pk2(c1[2] + bz, c1[3] + bz));
  llc_st64(p + 1024, pk2(c2[0] + bn, c2[1] + bn));
  llc_st64(p + 1280, pk2(c2[2] + bn, c2[3] + bn));
}
__device__ __forceinline__ void gh_load_soa(const u64* g, int lid, int wv, int lane,
                                            f4& g0, f4& g1, f4& g2)
{
  const u64* p = g + ((size_t)lid * 24 + wv) * 64 + lane;
  f2 a = __builtin_bit_cast(f2, llc_ld64(p));
  f2 b = __builtin_bit_cast(f2, llc_ld64(p + 256));
  f2 c = __builtin_bit_cast(f2, llc_ld64(p + 512));
  f2 d = __builtin_bit_cast(f2, llc_ld64(p + 768));
  f2 e = __builtin_bit_cast(f2, llc_ld64(p + 1024));
  f2 f = __builtin_bit_cast(f2, llc_ld64(p + 1280));
  g0[0] = a[0]; g0[1] = a[1]; g0[2] = b[0]; g0[3] = b[1];
  g1[0] = c[0]; g1[1] = c[1]; g1[2] = d[0]; g1[3] = d[1];
  g2[0] = e[0]; g2[1] = e[1]; g2[2] = f[0]; g2[3] = f[1];
}

// GRU elementwise; f32 master state in registers; bf16 mirror published to
// frag-major layout via lane-pair-packed u32 LLC stores.
__device__ __forceinline__ void gru_apply(f4 c0, f4 c1, f4 c2, f4 g0, f4 g1, f4 g2,
                                          float br, float bz, float bn,
                                          float hreg[4], bf16_t* __restrict__ hb,
                                          int hoff, int lo)
{
#pragma unroll
  for (int q = 0; q < 4; ++q) {
    float r = sigmoidf_(c0[q] + br + g0[q]);
    float z = sigmoidf_(c1[q] + bz + g1[q]);
    float n = tanhf_  (c2[q] + bn + r * g2[q]);
    float hv = (1.f - z) * n + z * hreg[q];
    hreg[q] = hv;
    unsigned my = (unsigned)__builtin_bit_cast(unsigned short, (bf16_t)hv);
    unsigned ot = __shfl_xor(my, 1, 64);
    if ((lo & 1) == 0)
      llc_st32((unsigned*)(hb + hoff + q * 8), my | (ot << 16));
  }
}

__global__ void __launch_bounds__(256, 1)
rnn_persist(const float* __restrict__ hidden, const float* __restrict__ frame0,
            const float* __restrict__ Wih0, const float* __restrict__ Whh0,
            const float* __restrict__ bih0, const float* __restrict__ bhh0,
            const float* __restrict__ Wih1, const float* __restrict__ Whh1,
            const float* __restrict__ bih1, const float* __restrict__ bhh1,
            const float* __restrict__ fcW, const float* __restrict__ fcb,
            float* __restrict__ out, char* __restrict__ ws)
{
  extern __shared__ char smem[];
  const int tid = threadIdx.x;
  const int bid = blockIdx.x;
  const int gid = bid >> 6;     // 0:gi0  1:gh0(+y)  2:gi1  3:gh1
  const int lid = bid & 63;     // h-columns [lid*16, lid*16+16)
  const int lane = tid & 63;
  const int wv = tid >> 6;      // wave = row-tile (16 batch rows)
  const int lo = lane & 15, hi = lane >> 4;

  unsigned* flags = (unsigned*)(ws + O_FLAGS);
  // wave-granular flags: [grp][wv][lid]
  unsigned* flgA0 = (unsigned*)(ws + O_FLG);          // G0: step t -> t+1
  unsigned* flgA3 = (unsigned*)(ws + O_FLG + 1024);   // G3: step t -> t+1
  unsigned* flgB1 = (unsigned*)(ws + O_FLG + 2048);   // G1: P1 -> 1; step t -> t+2
  unsigned* flgB2 = (unsigned*)(ws + O_FLG + 3072);   // G2: step t -> t+1
  float*  b0f  = (float*)(ws + O_B0F);
  bf16_t* x0b  = (bf16_t*)(ws + O_X0);
  bf16_t* h0b  = (bf16_t*)(ws + O_H0B);
  bf16_t* h1b  = (bf16_t*)(ws + O_H1B);   // [2][65536] frag-major ring
  u64*    gh0w = (u64*)(ws + O_GH0);
  u64*    gh1w = (u64*)(ws + O_GH1);
  bf16_t* w0fb = (bf16_t*)(ws + O_W0F);

  // ---- wave-granular sync primitives (no __syncthreads in main loop) ----
  auto signalw = [&](unsigned* arr, unsigned val) {
    sfence();
    asm volatile("s_waitcnt vmcnt(0)" ::: "memory");   // this wave's stores ack'd
    if (lane == 0) llc_st32(&arr[wv * 64 + lid], val);
  };
  auto waitw1 = [&](const unsigned* arr, unsigned g) {
    const unsigned* p = arr + wv * 64 + lane;
    while (!__all(llc_ld32(p) >= g)) {}
    sfence();
  };
  auto waitw2 = [&](const unsigned* a, unsigned ga, const unsigned* b, unsigned gb) {
    const unsigned* pa = a + wv * 64 + lane;
    const unsigned* pb = b + wv * 64 + lane;
    for (;;) {
      unsigned va = llc_ld32(pa);
      unsigned vb = llc_ld32(pb);
      if (__all(va >= ga && vb >= gb)) break;
    }
    sfence();
  };
  // ---- one-time heavy barrier after P0 (plain-store-initialized data) ----
  auto barrier_heavy = [&]() {
    __syncthreads();
    if (tid == 0)
      __hip_atomic_store(&flags[bid], 1u, __ATOMIC_RELEASE, __HIP_MEMORY_SCOPE_AGENT);
    if (tid < 64) {
      const u64* fp = (const u64*)(flags) + tid * 2;
      for (;;) {
        u64 a = llc_ld64(fp), b = llc_ld64(fp + 1);
        if ((unsigned)a && (unsigned)(a >> 32) && (unsigned)b && (unsigned)(b >> 32)) break;
        __builtin_amdgcn_s_sleep(1);
      }
    }
    __syncthreads();
    __builtin_amdgcn_fence(__ATOMIC_ACQUIRE, "agent");
    sfence();
  };

  const int col = lid * 16 + lo;
  // frag-major write offset for gru_apply (this thread's q=0 element):
  const int hoff = (wv * 32 + (lid >> 1)) * 512
                 + ((((lid & 1) << 1) + (lo >> 3)) * 16 + hi * 4) * 8 + (lo & 7);
  float hreg[4];

  // ================= P0: distributed prep =================
  {
    // bf16 mirrors of hidden, FRAG-MAJOR (h1 init into ring slot 1); plain stores
#pragma unroll
    for (int it = 0; it < 2; ++it) {
      int idx = bid * 512 + it * 256 + tid;   // 0..131071
      float v = hidden[idx];
      int layer = idx >> 16, rc = idx & 65535;
      int row = rc >> 10, c = rc & 1023;
      int f = ((row >> 4) * 32 + (c >> 5)) * 512 + (((c >> 3) & 3) * 16 + (row & 15)) * 8 + (c & 7);
      if (layer == 0) h0b[f] = (bf16_t)v;
      else            h1b[65536 + f] = (bf16_t)v;
    }
    if (gid == 0 || gid == 2) {
#pragma unroll
      for (int q = 0; q < 4; ++q) {
        int row = wv * 16 + hi * 4 + q;
        hreg[q] = hidden[(gid == 0 ? 0 : 65536) + (size_t)row * 1024 + col];
      }
    }
    if (bid < 32) {   // frame0 -> frag-major 64x128
      int idx = bid * 256 + tid;   // 0..8191
      int row = idx >> 7, c = idx & 127;
      int f = ((row >> 4) * 4 + (c >> 5)) * 512 + (((c >> 3) & 3) * 16 + (row & 15)) * 8 + (c & 7);
      x0b[f] = (bf16_t)frame0[idx];
    }

    // W0f = W_ih0 @ fc_W (rows [bid*12, bid*12+12)) and b0f = b_ih0 + W_ih0 @ fc_b
    float* wih  = (float*)smem;      // 12*128
    float* fcbl = wih + 1536;        // 128
    float* fcwt = fcbl + 128;        // 128*64
    const int jbase = bid * 12;
    for (int i = 0; i < 6; ++i) { int ii = tid + 256 * i; wih[ii] = Wih0[(size_t)jbase * 128 + ii]; }
    if (tid < 128) fcbl[tid] = fcb[tid];
    __syncthreads();
    if (tid < 12) {
      float s = bih0[jbase + tid];
      for (int c = 0; c < 128; ++c) s += wih[tid * 128 + c] * fcbl[c];
      b0f[jbase + tid] = s;
    }
    for (int kt = 0; kt < 16; ++kt) {
      __syncthreads();
      for (int i = 0; i < 32; ++i) {
        int ii = tid + 256 * i; int c = ii >> 6, x = ii & 63;
        fcwt[ii] = fcW[(size_t)c * 1024 + kt * 64 + x];
      }
      __syncthreads();
      int x = tid & 63, jg = tid >> 6;
      for (int jj = 0; jj < 3; ++jj) {
        int j = jg * 3 + jj;
        float s = 0.f;
#pragma unroll 16
        for (int c = 0; c < 128; ++c) s += wih[j * 128 + c] * fcwt[c * 64 + x];
        w0fb[(size_t)(jbase + j) * 1024 + kt * 64 + x] = (bf16_t)s;
      }
    }
  }
  barrier_heavy();   // one-time wbl2/inv; everything after is LLC-direct

  // hoisted per-group biases (read-only after P0)
  float brM = 0.f, bzM = 0.f, bnM = 0.f, br0 = 0.f, bz0 = 0.f, bn0 = 0.f, fcbr = 0.f;
  if (gid == 0) {
    brM = b0f[col]; bzM = b0f[1024 + col]; bnM = b0f[2048 + col];
    br0 = bih0[col]; bz0 = bih0[1024 + col]; bn0 = bih0[2048 + col];
  } else if (gid == 1) {
    brM = bhh0[col]; bzM = bhh0[1024 + col]; bnM = bhh0[2048 + col];
    if (lid < 8) fcbr = fcb[col];
  } else if (gid == 2) {
    brM = bih1[col]; bzM = bih1[1024 + col]; bnM = bih1[2048 + col];
  } else {
    brM = bhh1[col]; bzM = bhh1[1024 + col]; bnM = bhh1[2048 + col];
  }

  // ================= P1: stage LDS weights (persistent) =================
  {
    if (gid == 0) {
      for (int i = 0; i < 24; ++i) {              // W0f slice (bf16 src)
        int cc = tid + 256 * i;
        int w = cc >> 7, x = cc & 127;
        int g = w >> 4, r = w & 15;
        size_t grow = (size_t)g * 1024 + lid * 16 + r;
        bf8 v = *(const bf8*)(w0fb + grow * 1024 + x * 8);
        *(bf8*)(smem + w * 2048 + ((x ^ (w & 7)) * 16)) = v;
      }
      for (int i = 0; i < 3; ++i) {               // W_ih0 slice (K=128, t=0 path)
        int cc = tid + 256 * i;
        int w = cc >> 4, x = cc & 15;
        int g = w >> 4, r = w & 15;
        size_t grow = (size_t)g * 1024 + lid * 16 + r;
        const float* src = Wih0 + grow * 128 + x * 8;
        bf8 v;
#pragma unroll
        for (int e = 0; e < 8; ++e) v[e] = (bf16_t)src[e];
        *(bf8*)(smem + LDS_EXTRA + w * 256 + ((x ^ (w & 7)) * 16)) = v;
      }
    } else {
      const float* Wsrc = (gid == 1) ? Whh0 : (gid == 2) ? Wih1 : Whh1;
      for (int i = 0; i < 24; ++i) {
        int cc = tid + 256 * i;
        int w = cc >> 7, x = cc & 127;
        int g = w >> 4, r = w & 15;
        size_t grow = (size_t)g * 1024 + lid * 16 + r;
        const float* src = Wsrc + grow * 1024 + x * 8;
        bf8 v;
#pragma unroll
        for (int e = 0; e < 8; ++e) v[e] = (bf16_t)src[e];
        *(bf8*)(smem + w * 2048 + ((x ^ (w & 7)) * 16)) = v;
      }
      if (gid == 1 && lid < 8) {                  // fcW slice for y-GEMM
        for (int i = 0; i < 8; ++i) {
          int cc = tid + 256 * i;
          int w = cc >> 7, x = cc & 127;
          const float* src = fcW + (size_t)(lid * 16 + w) * 1024 + x * 8;
          bf8 v;
#pragma unroll
          for (int e = 0; e < 8; ++e) v[e] = (bf16_t)src[e];
          *(bf8*)(smem + LDS_EXTRA + w * 2048 + ((x ^ (w & 7)) * 16)) = v;
        }
      }
    }
    __syncthreads();   // LDS staging visible to all waves of this block
    if (gid == 1) {    // gh0 for t=0 (A = initial h0); per-wave signal B1 = 1
      f4 c0 = {0.f,0.f,0.f,0.f}, c1 = {0.f,0.f,0.f,0.f}, c2 = {0.f,0.f,0.f,0.f};
      gemm3<32, 2048>(h0b, (const char*)smem, lane, wv, c0, c1, c2);
      gh_store_soa(gh0w, lid, wv, lane, c0, c1, c2, brM, bzM, bnM);
      signalw(flgB1, 1);
    }
  }

  // ============ main loop: 256 steps, wave-granular point-to-point sync ============
  // flag values after step t: A0/A3/B2 = t+1; B1 = t+2 (P1 set it to 1).
  for (int t = 0; t < 256; ++t) {
    const bf16_t* h1prev = h1b + ((t + 1) & 1) * 65536;

    if (gid == 0) {
      if (t == 0) waitw1(flgB1, 1);
      else        waitw2(flgB1, (unsigned)(t + 1), flgB2, (unsigned)t);
      f4 g0, g1, g2;
      gh_load_soa(gh0w, lid, wv, lane, g0, g1, g2);   // RTT hides under gemm
      f4 c0 = {0.f,0.f,0.f,0.f}, c1 = {0.f,0.f,0.f,0.f}, c2 = {0.f,0.f,0.f,0.f};
      if (t == 0) {
        gemm3<4, 256>(x0b, (const char*)smem + LDS_EXTRA, lane, wv, c0, c1, c2);
        gru_apply(c0, c1, c2, g0, g1, g2, br0, bz0, bn0, hreg, h0b, hoff, lo);
      } else {
        gemm3<32, 2048>(h1prev, (const char*)smem, lane, wv, c0, c1, c2);
        gru_apply(c0, c1, c2, g0, g1, g2, brM, bzM, bnM, hreg, h0b, hoff, lo);
      }
      signalw(flgA0, (unsigned)(t + 1));
    } else if (gid == 3) {
      if (t > 0) waitw1(flgB2, (unsigned)t);          // h1[t-1] ready; gh1w[t-1] consumed
      f4 c0 = {0.f,0.f,0.f,0.f}, c1 = {0.f,0.f,0.f,0.f}, c2 = {0.f,0.f,0.f,0.f};
      gemm3<32, 2048>(h1prev, (const char*)smem, lane, wv, c0, c1, c2);
      gh_store_soa(gh1w, lid, wv, lane, c0, c1, c2, brM, bzM, bnM);
      signalw(flgA3, (unsigned)(t + 1));
    } else if (gid == 1) {
      waitw1(flgA0, (unsigned)(t + 1));               // h0[t] ready (implies B2 >= t)
      if (t < 255) {
        f4 c0 = {0.f,0.f,0.f,0.f}, c1 = {0.f,0.f,0.f,0.f}, c2 = {0.f,0.f,0.f,0.f};
        gemm3<32, 2048>(h0b, (const char*)smem, lane, wv, c0, c1, c2);
        gh_store_soa(gh0w, lid, wv, lane, c0, c1, c2, brM, bzM, bnM);
      }
      if (lid < 8 && t > 0) {                         // y_{t-1}; must precede B1 signal
        f4 y = gemm1(h1prev, (const char*)smem + LDS_EXTRA, lane, wv);
#pragma unroll
        for (int q = 0; q < 4; ++q) {
          int row = wv * 16 + hi * 4 + q;
          out[(size_t)row * 32768 + (size_t)col * 256 + (t - 1)] = y[q] + fcbr;
        }
      }
      signalw(flgB1, (unsigned)(t + 2));
    } else { // gid == 2
      waitw2(flgA0, (unsigned)(t + 1), flgA3, (unsigned)(t + 1));
      f4 g0, g1, g2;
      gh_load_soa(gh1w, lid, wv, lane, g0, g1, g2);   // RTT hides under gemm
      f4 c0 = {0.f,0.f,0.f,0.f}, c1 = {0.f,0.f,0.f,0.f}, c2 = {0.f,0.f,0.f,0.f};
      gemm3<32, 2048>(h0b, (const char*)smem, lane, wv, c0, c1, c2);
      gru_apply(c0, c1, c2, g0, g1, g2, brM, bzM, bnM, hreg,
                h1b + (t & 1) * 65536, hoff, lo);
      signalw(flgB2, (unsigned)(t + 1));
    }
  }

  // ---- epilogue: y_255 ----
  if (gid == 1 && lid < 8) {
    waitw1(flgB2, 256u);
    const bf16_t* h1last = h1b + 65536;   // slot 255&1 = 1
    f4 y = gemm1(h1last, (const char*)smem + LDS_EXTRA, lane, wv);
#pragma unroll
    for (int q = 0; q < 4; ++q) {
      int row = wv * 16 + hi * 4 + q;
      out[(size_t)row * 32768 + (size_t)col * 256 + 255] = y[q] + fcbr;
    }
  }
}

extern "C" void kernel_launch(void* const* d_in, const int* in_sizes, int n_in,
                              void* d_out, int out_size, void* d_ws, size_t ws_size,
                              hipStream_t stream)
{
  const float* hidden = (const float*)d_in[0];
  const float* frame0 = (const float*)d_in[1];
  const float* Wih0 = (const float*)d_in[2];
  const float* Whh0 = (const float*)d_in[3];
  const float* bih0 = (const float*)d_in[4];
  const float* bhh0 = (const float*)d_in[5];
  const float* Wih1 = (const float*)d_in[6];
  const float* Whh1 = (const float*)d_in[7];
  const float* bih1 = (const float*)d_in[8];
  const float* bhh1 = (const float*)d_in[9];
  const float* fcW  = (const float*)d_in[10];
  const float* fcb  = (const float*)d_in[11];
  float* out = (float*)d_out;
  char*  ws  = (char*)d_ws;

  hipMemsetAsync(ws, 0, 8192, stream);  // zero heavy flags + wave flags

  hipFuncSetAttribute((const void*)rnn_persist,
                      hipFuncAttributeMaxDynamicSharedMemorySize, LDS_SIZE);

  void* args[] = { (void*)&hidden, (void*)&frame0, (void*)&Wih0, (void*)&Whh0,
                   (void*)&bih0, (void*)&bhh0, (void*)&Wih1, (void*)&Whh1,
                   (void*)&bih1, (void*)&bhh1, (void*)&fcW, (void*)&fcb,
                   (void*)&out, (void*)&ws };
  hipError_t err = hipLaunchCooperativeKernel((const void*)rnn_persist,
                                              dim3(256), dim3(256), args, LDS_SIZE, stream);
  if (err != hipSuccess) {
    // co-residency is guaranteed anyway: 256 blocks, 1 block/CU (128KB LDS), 256 CUs
    rnn_persist<<<dim3(256), dim3(256), LDS_SIZE, stream>>>(
        hidden, frame0, Wih0, Whh0, bih0, bhh0, Wih1, Whh1, bih1, bhh1, fcW, fcb, out, ws);
  }
}

// Round 8
// 4254.858 us; speedup vs baseline: 1.2302x; 1.2302x over previous
//
#include <hip/hip_runtime.h>
#include <hip/hip_bf16.h>

// SeqDecoderRNN: 2-layer GRU decoder, B=64 H=1024 C=128 T=256.
// Persistent cooperative kernel: 256 blocks x 256 threads, weights LDS-resident.
// Groups of 64 blocks: G0=gi0(+h0 elementwise), G1=gh0 (+y GEMM on 8 blocks),
// G2=gi1(+h1 elementwise), G3=gh1.
// Sync: block-granular per-block generation FLAGS (no RMW): producer tid0
// stores flag[lid]; waiter wave reads all 64 group flags in ONE instruction,
// __all-ballots, s_sleep(1) backoff. All cross-block data via relaxed
// agent-scope atomics (LLC-direct). h mirrors frag-major; gh handoff SoA u64
// (each instruction covers 512B contiguous).
// sched_barrier(0) fences pin program order around sync (rule #18 — load-bearing).

typedef __bf16 bf16_t;
typedef __bf16 bf8 __attribute__((ext_vector_type(8)));
typedef float  f4  __attribute__((ext_vector_type(4)));
typedef float  f2  __attribute__((ext_vector_type(2)));
typedef unsigned long long u64;
typedef u64 u64x2 __attribute__((ext_vector_type(2)));

static constexpr unsigned O_FLAGS = 0;                    // 256 u32 heavy-barrier flags
static constexpr unsigned O_FLG   = 1024;                 // 4 groups x 64 u32, 1KB apart
static constexpr unsigned O_B0F   = 8192;                 // 3072 f32
static constexpr unsigned O_X0    = O_B0F + 12288;        // 64x128 bf16 (frag-major)
static constexpr unsigned O_H0B   = O_X0  + 16384;        // 64x1024 bf16 (frag-major)
static constexpr unsigned O_H1B   = O_H0B + 131072;       // 2 x 64x1024 bf16 ring (frag-major)
static constexpr unsigned O_GH0   = O_H1B + 262144;       // 64*6*4*64 u64 SoA
static constexpr unsigned O_GH1   = O_GH0 + 786432;       // 64*6*4*64 u64 SoA
static constexpr unsigned O_W0F   = O_GH1 + 786432;       // 3072x1024 bf16 (W_ih0 @ fc_W)

#define LDS_EXTRA 98304
#define LDS_SIZE  131072

__device__ __forceinline__ void sfence() { __builtin_amdgcn_sched_barrier(0); }

__device__ __forceinline__ float sigmoidf_(float x) { return 1.f / (1.f + __expf(-x)); }
__device__ __forceinline__ float tanhf_(float x) {
  float e = __expf(-2.f * fabsf(x));
  float t = (1.f - e) / (1.f + e);
  return x < 0.f ? -t : t;
}

// ---- LLC-direct (agent-scope relaxed atomic) access helpers ----
__device__ __forceinline__ u64 llc_ld64(const void* p) {
  return __hip_atomic_load((u64*)p, __ATOMIC_RELAXED, __HIP_MEMORY_SCOPE_AGENT);
}
__device__ __forceinline__ unsigned llc_ld32(const unsigned* p) {
  return __hip_atomic_load((unsigned*)p, __ATOMIC_RELAXED, __HIP_MEMORY_SCOPE_AGENT);
}
__device__ __forceinline__ void llc_st32(unsigned* p, unsigned v) {
  __hip_atomic_store(p, v, __ATOMIC_RELAXED, __HIP_MEMORY_SCOPE_AGENT);
}
__device__ __forceinline__ void llc_st64(u64* p, u64 v) {
  __hip_atomic_store(p, v, __ATOMIC_RELAXED, __HIP_MEMORY_SCOPE_AGENT);
}

// frag-major element index for a 64 x (NKS*32) matrix:
//   f(row,col) = ((row>>4)*NKS + (col>>5))*512 + (((col>>3)&3)*16 + (row&15))*8 + (col&7)

// 3-tile (r,z,n gates) GEMM: 16 rows x 48 cols per wave, K = NKS*32.
// A: frag-major bf16, LLC-direct, full prefetch. B: LDS XOR-swizzled, dbuf regs.
template<int NKS, int RS>
__device__ __forceinline__ void gemm3(const bf16_t* __restrict__ Afm,
                                      const char* lds, int lane, int rt,
                                      f4& c0, f4& c1, f4& c2)
{
  const int lo = lane & 15, hi = lane >> 4;
  const bf16_t* ap = Afm + (size_t)rt * (NKS * 512) + lane * 8;
  const int sw = lo & 7;
  const char* l0 = lds + lo * RS;
  const char* l1 = lds + (16 + lo) * RS;
  const char* l2 = lds + (32 + lo) * RS;
  u64 a0[NKS], a1[NKS];
#pragma unroll
  for (int p = 0; p < NKS; ++p) {
    a0[p] = llc_ld64(ap + p * 512);
    a1[p] = llc_ld64(ap + p * 512 + 4);
  }
  int xo0 = (hi ^ sw) * 16;
  bf8 b0 = *(const bf8*)(l0 + xo0);
  bf8 b1 = *(const bf8*)(l1 + xo0);
  bf8 b2 = *(const bf8*)(l2 + xo0);
#pragma unroll
  for (int ks = 0; ks < NKS; ++ks) {
    bf8 nb0, nb1, nb2;
    if (ks + 1 < NKS) {
      const int nxo = (((ks + 1) * 4 + hi) ^ sw) * 16;
      nb0 = *(const bf8*)(l0 + nxo);
      nb1 = *(const bf8*)(l1 + nxo);
      nb2 = *(const bf8*)(l2 + nxo);
    }
    u64x2 tt; tt.x = a0[ks]; tt.y = a1[ks];
    bf8 a = __builtin_bit_cast(bf8, tt);
    c0 = __builtin_amdgcn_mfma_f32_16x16x32_bf16(a, b0, c0, 0, 0, 0);
    c1 = __builtin_amdgcn_mfma_f32_16x16x32_bf16(a, b1, c1, 0, 0, 0);
    c2 = __builtin_amdgcn_mfma_f32_16x16x32_bf16(a, b2, c2, 0, 0, 0);
    b0 = nb0; b1 = nb1; b2 = nb2;
  }
}

// single-tile GEMM (y = h1 @ fcW^T slice): 16 rows x 16 cols per wave, K=1024.
__device__ __forceinline__ f4 gemm1(const bf16_t* __restrict__ Afm,
                                    const char* lds, int lane, int rt)
{
  const int lo = lane & 15, hi = lane >> 4;
  const bf16_t* ap = Afm + (size_t)rt * 16384 + lane * 8;
  const int sw = lo & 7;
  const char* lb = lds + lo * 2048;
  f4 acc = {0.f, 0.f, 0.f, 0.f};
  u64 a0[32], a1[32];
#pragma unroll
  for (int p = 0; p < 32; ++p) {
    a0[p] = llc_ld64(ap + p * 512);
    a1[p] = llc_ld64(ap + p * 512 + 4);
  }
  bf8 b = *(const bf8*)(lb + (hi ^ sw) * 16);
#pragma unroll
  for (int ks = 0; ks < 32; ++ks) {
    bf8 nb;
    if (ks + 1 < 32) nb = *(const bf8*)(lb + ((((ks + 1) * 4 + hi) ^ sw) * 16));
    u64x2 tt; tt.x = a0[ks]; tt.y = a1[ks];
    bf8 a = __builtin_bit_cast(bf8, tt);
    acc = __builtin_amdgcn_mfma_f32_16x16x32_bf16(a, b, acc, 0, 0, 0);
    b = nb;
  }
  return acc;
}

// gh handoff: SoA u64, index ((lid*6 + comp)*4 + wv)*64 + lane.
// Lane stride 8B -> each instruction covers 512B contiguous (no write amp).
// Producer thread (wv,lane) and consumer thread (wv,lane) hold identical elems.
__device__ __forceinline__ u64 pk2(float x, float y) {
  f2 v = {x, y}; return __builtin_bit_cast(u64, v);
}
__device__ __forceinline__ void gh_store_soa(u64* g, int lid, int wv, int lane,
                                             f4 c0, f4 c1, f4 c2,
                                             float br, float bz, float bn)
{
  u64* p = g + ((size_t)lid * 24 + wv) * 64 + lane;
  llc_st64(p,        pk2(c0[0] + br, c0[1] + br));
  llc_st64(p + 256,  pk2(c0[2] + br, c0[3] + br));
  llc_st64(p + 512,  pk2(c1[0] + bz, c1[1] + bz));
  llc_st64(p + 768,  pk2(c1[2] + bz, c1[3] + bz));
  llc_st64(p + 1024, pk2(c2[0] + bn, c2[1] + bn));
  llc_st64(p + 1280, pk2(c2[2] + bn, c2[3] + bn));
}
__device__ __forceinline__ void gh_load_soa(const u64* g, int lid, int wv, int lane,
                                            f4& g0, f4& g1, f4& g2)
{
  const u64* p = g + ((size_t)lid * 24 + wv) * 64 + lane;
  f2 a = __builtin_bit_cast(f2, llc_ld64(p));
  f2 b = __builtin_bit_cast(f2, llc_ld64(p + 256));
  f2 c = __builtin_bit_cast(f2, llc_ld64(p + 512));
  f2 d = __builtin_bit_cast(f2, llc_ld64(p + 768));
  f2 e = __builtin_bit_cast(f2, llc_ld64(p + 1024));
  f2 f = __builtin_bit_cast(f2, llc_ld64(p + 1280));
  g0[0] = a[0]; g0[1] = a[1]; g0[2] = b[0]; g0[3] = b[1];
  g1[0] = c[0]; g1[1] = c[1]; g1[2] = d[0]; g1[3] = d[1];
  g2[0] = e[0]; g2[1] = e[1]; g2[2] = f[0]; g2[3] = f[1];
}

// GRU elementwise; f32 master state in registers; bf16 mirror published to
// frag-major layout via lane-pair-packed u32 LLC stores.
__device__ __forceinline__ void gru_apply(f4 c0, f4 c1, f4 c2, f4 g0, f4 g1, f4 g2,
                                          float br, float bz, float bn,
                                          float hreg[4], bf16_t* __restrict__ hb,
                                          int hoff, int lo)
{
#pragma unroll
  for (int q = 0; q < 4; ++q) {
    float r = sigmoidf_(c0[q] + br + g0[q]);
    float z = sigmoidf_(c1[q] + bz + g1[q]);
    float n = tanhf_  (c2[q] + bn + r * g2[q]);
    float hv = (1.f - z) * n + z * hreg[q];
    hreg[q] = hv;
    unsigned my = (unsigned)__builtin_bit_cast(unsigned short, (bf16_t)hv);
    unsigned ot = __shfl_xor(my, 1, 64);
    if ((lo & 1) == 0)
      llc_st32((unsigned*)(hb + hoff + q * 8), my | (ot << 16));
  }
}

__global__ void __launch_bounds__(256, 1)
rnn_persist(const float* __restrict__ hidden, const float* __restrict__ frame0,
            const float* __restrict__ Wih0, const float* __restrict__ Whh0,
            const float* __restrict__ bih0, const float* __restrict__ bhh0,
            const float* __restrict__ Wih1, const float* __restrict__ Whh1,
            const float* __restrict__ bih1, const float* __restrict__ bhh1,
            const float* __restrict__ fcW, const float* __restrict__ fcb,
            float* __restrict__ out, char* __restrict__ ws)
{
  extern __shared__ char smem[];
  const int tid = threadIdx.x;
  const int bid = blockIdx.x;
  const int gid = bid >> 6;     // 0:gi0  1:gh0(+y)  2:gi1  3:gh1
  const int lid = bid & 63;     // h-columns [lid*16, lid*16+16)
  const int lane = tid & 63;
  const int wv = tid >> 6;      // wave = row-tile (16 batch rows)
  const int lo = lane & 15, hi = lane >> 4;

  unsigned* flags = (unsigned*)(ws + O_FLAGS);
  unsigned* flgA0 = (unsigned*)(ws + O_FLG);          // G0: step t -> t+1
  unsigned* flgA3 = (unsigned*)(ws + O_FLG + 1024);   // G3: step t -> t+1
  unsigned* flgB1 = (unsigned*)(ws + O_FLG + 2048);   // G1: P1 -> 1; step t -> t+2
  unsigned* flgB2 = (unsigned*)(ws + O_FLG + 3072);   // G2: step t -> t+1
  float*  b0f  = (float*)(ws + O_B0F);
  bf16_t* x0b  = (bf16_t*)(ws + O_X0);
  bf16_t* h0b  = (bf16_t*)(ws + O_H0B);
  bf16_t* h1b  = (bf16_t*)(ws + O_H1B);   // [2][65536] frag-major ring
  u64*    gh0w = (u64*)(ws + O_GH0);
  u64*    gh1w = (u64*)(ws + O_GH1);
  bf16_t* w0fb = (bf16_t*)(ws + O_W0F);

  // ---- block-granular sync: per-block flag store (no RMW); one wave polls all
  // 64 group flags with a single load instruction; s_sleep backoff ----
  auto signal_flag = [&](unsigned* arr, unsigned val) {
    sfence();
    asm volatile("s_waitcnt vmcnt(0)" ::: "memory");   // all LLC stores ack'd
    __syncthreads();                                    // all waves of block done
    if (tid == 0) llc_st32(&arr[lid], val);
  };
  auto wait1 = [&](const unsigned* arr, unsigned g) {
    if (tid < 64) {
      while (!__all(llc_ld32(&arr[tid]) >= g)) __builtin_amdgcn_s_sleep(1);
    }
    __syncthreads();
    sfence();
  };
  auto wait2 = [&](const unsigned* a, unsigned ga, const unsigned* b, unsigned gb) {
    if (tid < 64) {
      for (;;) {
        unsigned va = llc_ld32(&a[tid]);
        unsigned vb = llc_ld32(&b[tid]);
        if (__all(va >= ga && vb >= gb)) break;
        __builtin_amdgcn_s_sleep(1);
      }
    }
    __syncthreads();
    sfence();
  };
  // ---- one-time heavy barrier after P0 (plain-store-initialized data) ----
  auto barrier_heavy = [&]() {
    __syncthreads();
    if (tid == 0)
      __hip_atomic_store(&flags[bid], 1u, __ATOMIC_RELEASE, __HIP_MEMORY_SCOPE_AGENT);
    if (tid < 64) {
      const u64* fp = (const u64*)(flags) + tid * 2;
      for (;;) {
        u64 a = llc_ld64(fp), b = llc_ld64(fp + 1);
        if ((unsigned)a && (unsigned)(a >> 32) && (unsigned)b && (unsigned)(b >> 32)) break;
        __builtin_amdgcn_s_sleep(1);
      }
    }
    __syncthreads();
    __builtin_amdgcn_fence(__ATOMIC_ACQUIRE, "agent");
    sfence();
  };

  const int col = lid * 16 + lo;
  // frag-major write offset for gru_apply (this thread's q=0 element):
  const int hoff = (wv * 32 + (lid >> 1)) * 512
                 + ((((lid & 1) << 1) + (lo >> 3)) * 16 + hi * 4) * 8 + (lo & 7);
  float hreg[4];

  // ================= P0: distributed prep =================
  {
    // bf16 mirrors of hidden, FRAG-MAJOR (h1 init into ring slot 1); plain stores
#pragma unroll
    for (int it = 0; it < 2; ++it) {
      int idx = bid * 512 + it * 256 + tid;   // 0..131071
      float v = hidden[idx];
      int layer = idx >> 16, rc = idx & 65535;
      int row = rc >> 10, c = rc & 1023;
      int f = ((row >> 4) * 32 + (c >> 5)) * 512 + (((c >> 3) & 3) * 16 + (row & 15)) * 8 + (c & 7);
      if (layer == 0) h0b[f] = (bf16_t)v;
      else            h1b[65536 + f] = (bf16_t)v;
    }
    if (gid == 0 || gid == 2) {
#pragma unroll
      for (int q = 0; q < 4; ++q) {
        int row = wv * 16 + hi * 4 + q;
        hreg[q] = hidden[(gid == 0 ? 0 : 65536) + (size_t)row * 1024 + col];
      }
    }
    if (bid < 32) {   // frame0 -> frag-major 64x128
      int idx = bid * 256 + tid;   // 0..8191
      int row = idx >> 7, c = idx & 127;
      int f = ((row >> 4) * 4 + (c >> 5)) * 512 + (((c >> 3) & 3) * 16 + (row & 15)) * 8 + (c & 7);
      x0b[f] = (bf16_t)frame0[idx];
    }

    // W0f = W_ih0 @ fc_W (rows [bid*12, bid*12+12)) and b0f = b_ih0 + W_ih0 @ fc_b
    float* wih  = (float*)smem;      // 12*128
    float* fcbl = wih + 1536;        // 128
    float* fcwt = fcbl + 128;        // 128*64
    const int jbase = bid * 12;
    for (int i = 0; i < 6; ++i) { int ii = tid + 256 * i; wih[ii] = Wih0[(size_t)jbase * 128 + ii]; }
    if (tid < 128) fcbl[tid] = fcb[tid];
    __syncthreads();
    if (tid < 12) {
      float s = bih0[jbase + tid];
      for (int c = 0; c < 128; ++c) s += wih[tid * 128 + c] * fcbl[c];
      b0f[jbase + tid] = s;
    }
    for (int kt = 0; kt < 16; ++kt) {
      __syncthreads();
      for (int i = 0; i < 32; ++i) {
        int ii = tid + 256 * i; int c = ii >> 6, x = ii & 63;
        fcwt[ii] = fcW[(size_t)c * 1024 + kt * 64 + x];
      }
      __syncthreads();
      int x = tid & 63, jg = tid >> 6;
      for (int jj = 0; jj < 3; ++jj) {
        int j = jg * 3 + jj;
        float s = 0.f;
#pragma unroll 16
        for (int c = 0; c < 128; ++c) s += wih[j * 128 + c] * fcwt[c * 64 + x];
        w0fb[(size_t)(jbase + j) * 1024 + kt * 64 + x] = (bf16_t)s;
      }
    }
  }
  barrier_heavy();   // one-time wbl2/inv; everything after is LLC-direct

  // hoisted per-group biases (read-only after P0)
  float brM = 0.f, bzM = 0.f, bnM = 0.f, br0 = 0.f, bz0 = 0.f, bn0 = 0.f, fcbr = 0.f;
  if (gid == 0) {
    brM = b0f[col]; bzM = b0f[1024 + col]; bnM = b0f[2048 + col];
    br0 = bih0[col]; bz0 = bih0[1024 + col]; bn0 = bih0[2048 + col];
  } else if (gid == 1) {
    brM = bhh0[col]; bzM = bhh0[1024 + col]; bnM = bhh0[2048 + col];
    if (lid < 8) fcbr = fcb[col];
  } else if (gid == 2) {
    brM = bih1[col]; bzM = bih1[1024 + col]; bnM = bih1[2048 + col];
  } else {
    brM = bhh1[col]; bzM = bhh1[1024 + col]; bnM = bhh1[2048 + col];
  }

  // ================= P1: stage LDS weights (persistent) =================
  {
    if (gid == 0) {
      for (int i = 0; i < 24; ++i) {              // W0f slice (bf16 src)
        int cc = tid + 256 * i;
        int w = cc >> 7, x = cc & 127;
        int g = w >> 4, r = w & 15;
        size_t grow = (size_t)g * 1024 + lid * 16 + r;
        bf8 v = *(const bf8*)(w0fb + grow * 1024 + x * 8);
        *(bf8*)(smem + w * 2048 + ((x ^ (w & 7)) * 16)) = v;
      }
      for (int i = 0; i < 3; ++i) {               // W_ih0 slice (K=128, t=0 path)
        int cc = tid + 256 * i;
        int w = cc >> 4, x = cc & 15;
        int g = w >> 4, r = w & 15;
        size_t grow = (size_t)g * 1024 + lid * 16 + r;
        const float* src = Wih0 + grow * 128 + x * 8;
        bf8 v;
#pragma unroll
        for (int e = 0; e < 8; ++e) v[e] = (bf16_t)src[e];
        *(bf8*)(smem + LDS_EXTRA + w * 256 + ((x ^ (w & 7)) * 16)) = v;
      }
    } else {
      const float* Wsrc = (gid == 1) ? Whh0 : (gid == 2) ? Wih1 : Whh1;
      for (int i = 0; i < 24; ++i) {
        int cc = tid + 256 * i;
        int w = cc >> 7, x = cc & 127;
        int g = w >> 4, r = w & 15;
        size_t grow = (size_t)g * 1024 + lid * 16 + r;
        const float* src = Wsrc + grow * 1024 + x * 8;
        bf8 v;
#pragma unroll
        for (int e = 0; e < 8; ++e) v[e] = (bf16_t)src[e];
        *(bf8*)(smem + w * 2048 + ((x ^ (w & 7)) * 16)) = v;
      }
      if (gid == 1 && lid < 8) {                  // fcW slice for y-GEMM
        for (int i = 0; i < 8; ++i) {
          int cc = tid + 256 * i;
          int w = cc >> 7, x = cc & 127;
          const float* src = fcW + (size_t)(lid * 16 + w) * 1024 + x * 8;
          bf8 v;
#pragma unroll
          for (int e = 0; e < 8; ++e) v[e] = (bf16_t)src[e];
          *(bf8*)(smem + LDS_EXTRA + w * 2048 + ((x ^ (w & 7)) * 16)) = v;
        }
      }
    }
    if (gid == 1) {   // gh0 for t=0 (A = initial h0); sets flgB1 = 1
      __syncthreads();
      f4 c0 = {0.f,0.f,0.f,0.f}, c1 = {0.f,0.f,0.f,0.f}, c2 = {0.f,0.f,0.f,0.f};
      gemm3<32, 2048>(h0b, (const char*)smem, lane, wv, c0, c1, c2);
      gh_store_soa(gh0w, lid, wv, lane, c0, c1, c2, brM, bzM, bnM);
      signal_flag(flgB1, 1);
    }
  }

  // ============ main loop: 256 steps, block-granular point-to-point flags ============
  // flag values after step t: A0/A3/B2 = t+1; B1 = t+2 (P1 set it to 1).
  for (int t = 0; t < 256; ++t) {
    const bf16_t* h1prev = h1b + ((t + 1) & 1) * 65536;

    if (gid == 0) {
      if (t == 0) wait1(flgB1, 1);
      else        wait2(flgB1, (unsigned)(t + 1), flgB2, (unsigned)t);
      f4 g0, g1, g2;
      gh_load_soa(gh0w, lid, wv, lane, g0, g1, g2);   // RTT hides under gemm
      f4 c0 = {0.f,0.f,0.f,0.f}, c1 = {0.f,0.f,0.f,0.f}, c2 = {0.f,0.f,0.f,0.f};
      if (t == 0) {
        gemm3<4, 256>(x0b, (const char*)smem + LDS_EXTRA, lane, wv, c0, c1, c2);
        gru_apply(c0, c1, c2, g0, g1, g2, br0, bz0, bn0, hreg, h0b, hoff, lo);
      } else {
        gemm3<32, 2048>(h1prev, (const char*)smem, lane, wv, c0, c1, c2);
        gru_apply(c0, c1, c2, g0, g1, g2, brM, bzM, bnM, hreg, h0b, hoff, lo);
      }
      signal_flag(flgA0, (unsigned)(t + 1));
    } else if (gid == 3) {
      if (t > 0) wait1(flgB2, (unsigned)t);           // h1[t-1] ready; gh1w[t-1] consumed
      f4 c0 = {0.f,0.f,0.f,0.f}, c1 = {0.f,0.f,0.f,0.f}, c2 = {0.f,0.f,0.f,0.f};
      gemm3<32, 2048>(h1prev, (const char*)smem, lane, wv, c0, c1, c2);
      gh_store_soa(gh1w, lid, wv, lane, c0, c1, c2, brM, bzM, bnM);
      signal_flag(flgA3, (unsigned)(t + 1));
    } else if (gid == 1) {
      if (lid < 8 && t > 0) {                         // y_{t-1}: off critical path
        wait1(flgB2, (unsigned)t);
        f4 y = gemm1(h1prev, (const char*)smem + LDS_EXTRA, lane, wv);
#pragma unroll
        for (int q = 0; q < 4; ++q) {
          int row = wv * 16 + hi * 4 + q;
          out[(size_t)row * 32768 + (size_t)col * 256 + (t - 1)] = y[q] + fcbr;
        }
      }
      wait1(flgA0, (unsigned)(t + 1));                // h0[t] ready
      if (t < 255) {
        f4 c0 = {0.f,0.f,0.f,0.f}, c1 = {0.f,0.f,0.f,0.f}, c2 = {0.f,0.f,0.f,0.f};
        gemm3<32, 2048>(h0b, (const char*)smem, lane, wv, c0, c1, c2);
        gh_store_soa(gh0w, lid, wv, lane, c0, c1, c2, brM, bzM, bnM);
      }
      signal_flag(flgB1, (unsigned)(t + 2));
    } else { // gid == 2
      wait2(flgA0, (unsigned)(t + 1), flgA3, (unsigned)(t + 1));
      f4 g0, g1, g2;
      gh_load_soa(gh1w, lid, wv, lane, g0, g1, g2);   // RTT hides under gemm
      f4 c0 = {0.f,0.f,0.f,0.f}, c1 = {0.f,0.f,0.f,0.f}, c2 = {0.f,0.f,0.f,0.f};
      gemm3<32, 2048>(h0b, (const char*)smem, lane, wv, c0, c1, c2);
      gru_apply(c0, c1, c2, g0, g1, g2, brM, bzM, bnM, hreg,
                h1b + (t & 1) * 65536, hoff, lo);
      signal_flag(flgB2, (unsigned)(t + 1));
    }
  }

  // ---- epilogue: y_255 ----
  if (gid == 1 && lid < 8) {
    wait1(flgB2, 256u);
    const bf16_t* h1last = h1b + 65536;   // slot 255&1 = 1
    f4 y = gemm1(h1last, (const char*)smem + LDS_EXTRA, lane, wv);
#pragma unroll
    for (int q = 0; q < 4; ++q) {
      int row = wv * 16 + hi * 4 + q;
      out[(size_t)row * 32768 + (size_t)col * 256 + 255] = y[q] + fcbr;
    }
  }
}

extern "C" void kernel_launch(void* const* d_in, const int* in_sizes, int n_in,
                              void* d_out, int out_size, void* d_ws, size_t ws_size,
                              hipStream_t stream)
{
  const float* hidden = (const float*)d_in[0];
  const float* frame0 = (const float*)d_in[1];
  const float* Wih0 = (const float*)d_in[2];
  const float* Whh0 = (const float*)d_in[3];
  const float* bih0 = (const float*)d_in[4];
  const float* bhh0 = (const float*)d_in[5];
  const float* Wih1 = (const float*)d_in[6];
  const float* Whh1 = (const float*)d_in[7];
  const float* bih1 = (const float*)d_in[8];
  const float* bhh1 = (const float*)d_in[9];
  const float* fcW  = (const float*)d_in[10];
  const float* fcb  = (const float*)d_in[11];
  float* out = (float*)d_out;
  char*  ws  = (char*)d_ws;

  hipMemsetAsync(ws, 0, 8192, stream);  // zero heavy flags + group flags

  hipFuncSetAttribute((const void*)rnn_persist,
                      hipFuncAttributeMaxDynamicSharedMemorySize, LDS_SIZE);

  void* args[] = { (void*)&hidden, (void*)&frame0, (void*)&Wih0, (void*)&Whh0,
                   (void*)&bih0, (void*)&bhh0, (void*)&Wih1, (void*)&Whh1,
                   (void*)&bih1, (void*)&bhh1, (void*)&fcW, (void*)&fcb,
                   (void*)&out, (void*)&ws };
  hipError_t err = hipLaunchCooperativeKernel((const void*)rnn_persist,
                                              dim3(256), dim3(256), args, LDS_SIZE, stream);
  if (err != hipSuccess) {
    // co-residency is guaranteed anyway: 256 blocks, 1 block/CU (128KB LDS), 256 CUs
    rnn_persist<<<dim3(256), dim3(256), LDS_SIZE, stream>>>(
        hidden, frame0, Wih0, Whh0, bih0, bhh0, Wih1, Whh1, bih1, bhh1, fcW, fcb, out, ws);
  }
}

// Round 9
// 4159.050 us; speedup vs baseline: 1.2585x; 1.0230x over previous
//
#include <hip/hip_runtime.h>
#include <hip/hip_bf16.h>

// SeqDecoderRNN: 2-layer GRU decoder, B=64 H=1024 C=128 T=256.
// Persistent cooperative kernel: 256 blocks x 256 threads, weights LDS-resident.
// Groups of 64 blocks: G0=gi0(+h0 elementwise), G1=gh0 (+y GEMM on 8 blocks),
// G2=gi1(+h1 elementwise), G3=gh1.
// Sync: block-granular per-block generation FLAGS (no RMW), s_sleep backoff.
// Cross-block data: LLC-direct via 16B global_load/store_dwordx4 sc0 sc1
// (L1/L2 bypass; atomicity unnecessary — data quiescent under flag ordering).
// h mirrors frag-major; gh handoff [lid][gate][wv][lane][4f32] (16B/lane).
// sched_barrier(0) fences pin program order around sync + after asm waitcnt
// (rule #18 — load-bearing).

typedef __bf16 bf16_t;
typedef __bf16 bf8 __attribute__((ext_vector_type(8)));
typedef float  f4  __attribute__((ext_vector_type(4)));
typedef int    i4  __attribute__((ext_vector_type(4)));
typedef unsigned long long u64;

static constexpr unsigned O_FLAGS = 0;                    // 256 u32 heavy-barrier flags
static constexpr unsigned O_FLG   = 1024;                 // 4 groups x 64 u32, 1KB apart
static constexpr unsigned O_B0F   = 8192;                 // 3072 f32
static constexpr unsigned O_X0    = O_B0F + 12288;        // 64x128 bf16 (frag-major)
static constexpr unsigned O_H0B   = O_X0  + 16384;        // 64x1024 bf16 (frag-major)
static constexpr unsigned O_H1B   = O_H0B + 131072;       // 2 x 64x1024 bf16 ring (frag-major)
static constexpr unsigned O_GH0   = O_H1B + 262144;       // 64x3x4x64 f4 (16B/lane SoA)
static constexpr unsigned O_GH1   = O_GH0 + 786432;       // 64x3x4x64 f4
static constexpr unsigned O_W0F   = O_GH1 + 786432;       // 3072x1024 bf16 (W_ih0 @ fc_W)

#define LDS_EXTRA 98304
#define LDS_SIZE  131072

__device__ __forceinline__ void sfence() { __builtin_amdgcn_sched_barrier(0); }
__device__ __forceinline__ void vmwait() { asm volatile("s_waitcnt vmcnt(0)" ::: "memory"); }

__device__ __forceinline__ float sigmoidf_(float x) { return 1.f / (1.f + __expf(-x)); }
__device__ __forceinline__ float tanhf_(float x) {
  float e = __expf(-2.f * fabsf(x));
  float t = (1.f - e) / (1.f + e);
  return x < 0.f ? -t : t;
}

// ---- LLC-direct access: 16B loads/stores with sc0 sc1 (bypass L1/L2) ----
__device__ __forceinline__ i4 llc_ld128(const void* p) {
  i4 r;
  asm volatile("global_load_dwordx4 %0, %1, off sc0 sc1" : "=v"(r) : "v"(p) : "memory");
  return r;
}
__device__ __forceinline__ void llc_st128(void* p, i4 v) {
  asm volatile("global_store_dwordx4 %0, %1, off sc0 sc1" : : "v"(p), "v"(v) : "memory");
}
// 32/64-bit relaxed agent atomics (flags, h-publish)
__device__ __forceinline__ u64 llc_ld64(const void* p) {
  return __hip_atomic_load((u64*)p, __ATOMIC_RELAXED, __HIP_MEMORY_SCOPE_AGENT);
}
__device__ __forceinline__ unsigned llc_ld32(const unsigned* p) {
  return __hip_atomic_load((unsigned*)p, __ATOMIC_RELAXED, __HIP_MEMORY_SCOPE_AGENT);
}
__device__ __forceinline__ void llc_st32(unsigned* p, unsigned v) {
  __hip_atomic_store(p, v, __ATOMIC_RELAXED, __HIP_MEMORY_SCOPE_AGENT);
}

// frag-major element index for a 64 x (NKS*32) matrix:
//   f(row,col) = ((row>>4)*NKS + (col>>5))*512 + (((col>>3)&3)*16 + (row&15))*8 + (col&7)

// 3-tile (r,z,n gates) GEMM: 16 rows x 48 cols per wave, K = NKS*32.
// A: frag-major bf16, LLC-direct 16B loads (1 per fragment), all in flight,
// then one vmcnt(0)+sched_barrier. B: LDS XOR-swizzled.
template<int NKS, int RS>
__device__ __forceinline__ void gemm3(const bf16_t* __restrict__ Afm,
                                      const char* lds, int lane, int rt,
                                      f4& c0, f4& c1, f4& c2)
{
  const int lo = lane & 15, hi = lane >> 4;
  const bf16_t* ap = Afm + (size_t)rt * (NKS * 512) + lane * 8;
  const int sw = lo & 7;
  const char* l0 = lds + lo * RS;
  const char* l1 = lds + (16 + lo) * RS;
  const char* l2 = lds + (32 + lo) * RS;
  i4 areg[NKS];
#pragma unroll
  for (int p = 0; p < NKS; ++p) areg[p] = llc_ld128(ap + p * 512);
  vmwait(); sfence();
#pragma unroll
  for (int ks = 0; ks < NKS; ++ks) {
    const int xo = ((ks * 4 + hi) ^ sw) * 16;
    bf8 b0 = *(const bf8*)(l0 + xo);
    bf8 b1 = *(const bf8*)(l1 + xo);
    bf8 b2 = *(const bf8*)(l2 + xo);
    bf8 a = __builtin_bit_cast(bf8, areg[ks]);
    c0 = __builtin_amdgcn_mfma_f32_16x16x32_bf16(a, b0, c0, 0, 0, 0);
    c1 = __builtin_amdgcn_mfma_f32_16x16x32_bf16(a, b1, c1, 0, 0, 0);
    c2 = __builtin_amdgcn_mfma_f32_16x16x32_bf16(a, b2, c2, 0, 0, 0);
  }
}

// single-tile GEMM (y = h1 @ fcW^T slice): 16 rows x 16 cols per wave, K=1024.
__device__ __forceinline__ f4 gemm1(const bf16_t* __restrict__ Afm,
                                    const char* lds, int lane, int rt)
{
  const int lo = lane & 15, hi = lane >> 4;
  const bf16_t* ap = Afm + (size_t)rt * 16384 + lane * 8;
  const int sw = lo & 7;
  const char* lb = lds + lo * 2048;
  f4 acc = {0.f, 0.f, 0.f, 0.f};
  i4 areg[32];
#pragma unroll
  for (int p = 0; p < 32; ++p) areg[p] = llc_ld128(ap + p * 512);
  vmwait(); sfence();
#pragma unroll
  for (int ks = 0; ks < 32; ++ks) {
    bf8 b = *(const bf8*)(lb + (((ks * 4 + hi) ^ sw) * 16));
    bf8 a = __builtin_bit_cast(bf8, areg[ks]);
    acc = __builtin_amdgcn_mfma_f32_16x16x32_bf16(a, b, acc, 0, 0, 0);
  }
  return acc;
}

// gh handoff: f4 array, index (lid*12 + wv)*64 + lane, gate g at +g*256.
// Each lane's gate-quad is 16B contiguous; wave instruction covers 1KB.
__device__ __forceinline__ void gh_store_soa(f4* g, int lid, int wv, int lane,
                                             f4 c0, f4 c1, f4 c2,
                                             float br, float bz, float bn)
{
  f4* p = g + ((size_t)lid * 12 + wv) * 64 + lane;
  f4 v0 = {c0[0] + br, c0[1] + br, c0[2] + br, c0[3] + br};
  f4 v1 = {c1[0] + bz, c1[1] + bz, c1[2] + bz, c1[3] + bz};
  f4 v2 = {c2[0] + bn, c2[1] + bn, c2[2] + bn, c2[3] + bn};
  llc_st128(p,       __builtin_bit_cast(i4, v0));
  llc_st128(p + 256, __builtin_bit_cast(i4, v1));
  llc_st128(p + 512, __builtin_bit_cast(i4, v2));
}
__device__ __forceinline__ void gh_issue(const f4* g, int lid, int wv, int lane,
                                         i4& r0, i4& r1, i4& r2)
{
  const f4* p = g + ((size_t)lid * 12 + wv) * 64 + lane;
  r0 = llc_ld128(p);
  r1 = llc_ld128(p + 256);
  r2 = llc_ld128(p + 512);
}

// GRU elementwise; f32 master state in registers; bf16 mirror published to
// frag-major layout via lane-pair-packed u32 LLC stores.
__device__ __forceinline__ void gru_apply(f4 c0, f4 c1, f4 c2, f4 g0, f4 g1, f4 g2,
                                          float br, float bz, float bn,
                                          float hreg[4], bf16_t* __restrict__ hb,
                                          int hoff, int lo)
{
#pragma unroll
  for (int q = 0; q < 4; ++q) {
    float r = sigmoidf_(c0[q] + br + g0[q]);
    float z = sigmoidf_(c1[q] + bz + g1[q]);
    float n = tanhf_  (c2[q] + bn + r * g2[q]);
    float hv = (1.f - z) * n + z * hreg[q];
    hreg[q] = hv;
    unsigned my = (unsigned)__builtin_bit_cast(unsigned short, (bf16_t)hv);
    unsigned ot = __shfl_xor(my, 1, 64);
    if ((lo & 1) == 0)
      llc_st32((unsigned*)(hb + hoff + q * 8), my | (ot << 16));
  }
}

__global__ void __launch_bounds__(256, 1)
rnn_persist(const float* __restrict__ hidden, const float* __restrict__ frame0,
            const float* __restrict__ Wih0, const float* __restrict__ Whh0,
            const float* __restrict__ bih0, const float* __restrict__ bhh0,
            const float* __restrict__ Wih1, const float* __restrict__ Whh1,
            const float* __restrict__ bih1, const float* __restrict__ bhh1,
            const float* __restrict__ fcW, const float* __restrict__ fcb,
            float* __restrict__ out, char* __restrict__ ws)
{
  extern __shared__ char smem[];
  const int tid = threadIdx.x;
  const int bid = blockIdx.x;
  const int gid = bid >> 6;     // 0:gi0  1:gh0(+y)  2:gi1  3:gh1
  const int lid = bid & 63;     // h-columns [lid*16, lid*16+16)
  const int lane = tid & 63;
  const int wv = tid >> 6;      // wave = row-tile (16 batch rows)
  const int lo = lane & 15, hi = lane >> 4;

  unsigned* flags = (unsigned*)(ws + O_FLAGS);
  unsigned* flgA0 = (unsigned*)(ws + O_FLG);          // G0: step t -> t+1
  unsigned* flgA3 = (unsigned*)(ws + O_FLG + 1024);   // G3: step t -> t+1
  unsigned* flgB1 = (unsigned*)(ws + O_FLG + 2048);   // G1: P1 -> 1; step t -> t+2
  unsigned* flgB2 = (unsigned*)(ws + O_FLG + 3072);   // G2: step t -> t+1
  float*  b0f  = (float*)(ws + O_B0F);
  bf16_t* x0b  = (bf16_t*)(ws + O_X0);
  bf16_t* h0b  = (bf16_t*)(ws + O_H0B);
  bf16_t* h1b  = (bf16_t*)(ws + O_H1B);   // [2][65536] frag-major ring
  f4*     gh0w = (f4*)(ws + O_GH0);
  f4*     gh1w = (f4*)(ws + O_GH1);
  bf16_t* w0fb = (bf16_t*)(ws + O_W0F);

  // ---- block-granular sync: per-block flag store (no RMW); one wave polls all
  // 64 group flags with a single load instruction; s_sleep backoff ----
  auto signal_flag = [&](unsigned* arr, unsigned val) {
    sfence();
    vmwait();                                          // all LLC stores ack'd
    __syncthreads();                                   // all waves of block done
    if (tid == 0) llc_st32(&arr[lid], val);
  };
  auto wait1 = [&](const unsigned* arr, unsigned g) {
    if (tid < 64) {
      while (!__all(llc_ld32(&arr[tid]) >= g)) __builtin_amdgcn_s_sleep(1);
    }
    __syncthreads();
    sfence();
  };
  auto wait2 = [&](const unsigned* a, unsigned ga, const unsigned* b, unsigned gb) {
    if (tid < 64) {
      for (;;) {
        unsigned va = llc_ld32(&a[tid]);
        unsigned vb = llc_ld32(&b[tid]);
        if (__all(va >= ga && vb >= gb)) break;
        __builtin_amdgcn_s_sleep(1);
      }
    }
    __syncthreads();
    sfence();
  };
  // ---- one-time heavy barrier after P0 (plain-store-initialized data) ----
  auto barrier_heavy = [&]() {
    __syncthreads();
    if (tid == 0)
      __hip_atomic_store(&flags[bid], 1u, __ATOMIC_RELEASE, __HIP_MEMORY_SCOPE_AGENT);
    if (tid < 64) {
      const u64* fp = (const u64*)(flags) + tid * 2;
      for (;;) {
        u64 a = llc_ld64(fp), b = llc_ld64(fp + 1);
        if ((unsigned)a && (unsigned)(a >> 32) && (unsigned)b && (unsigned)(b >> 32)) break;
        __builtin_amdgcn_s_sleep(1);
      }
    }
    __syncthreads();
    __builtin_amdgcn_fence(__ATOMIC_ACQUIRE, "agent");
    sfence();
  };

  const int col = lid * 16 + lo;
  // frag-major write offset for gru_apply (this thread's q=0 element):
  const int hoff = (wv * 32 + (lid >> 1)) * 512
                 + ((((lid & 1) << 1) + (lo >> 3)) * 16 + hi * 4) * 8 + (lo & 7);
  float hreg[4];

  // ================= P0: distributed prep =================
  {
    // bf16 mirrors of hidden, FRAG-MAJOR (h1 init into ring slot 1); plain stores
#pragma unroll
    for (int it = 0; it < 2; ++it) {
      int idx = bid * 512 + it * 256 + tid;   // 0..131071
      float v = hidden[idx];
      int layer = idx >> 16, rc = idx & 65535;
      int row = rc >> 10, c = rc & 1023;
      int f = ((row >> 4) * 32 + (c >> 5)) * 512 + (((c >> 3) & 3) * 16 + (row & 15)) * 8 + (c & 7);
      if (layer == 0) h0b[f] = (bf16_t)v;
      else            h1b[65536 + f] = (bf16_t)v;
    }
    if (gid == 0 || gid == 2) {
#pragma unroll
      for (int q = 0; q < 4; ++q) {
        int row = wv * 16 + hi * 4 + q;
        hreg[q] = hidden[(gid == 0 ? 0 : 65536) + (size_t)row * 1024 + col];
      }
    }
    if (bid < 32) {   // frame0 -> frag-major 64x128
      int idx = bid * 256 + tid;   // 0..8191
      int row = idx >> 7, c = idx & 127;
      int f = ((row >> 4) * 4 + (c >> 5)) * 512 + (((c >> 3) & 3) * 16 + (row & 15)) * 8 + (c & 7);
      x0b[f] = (bf16_t)frame0[idx];
    }

    // W0f = W_ih0 @ fc_W (rows [bid*12, bid*12+12)) and b0f = b_ih0 + W_ih0 @ fc_b
    float* wih  = (float*)smem;      // 12*128
    float* fcbl = wih + 1536;        // 128
    float* fcwt = fcbl + 128;        // 128*64
    const int jbase = bid * 12;
    for (int i = 0; i < 6; ++i) { int ii = tid + 256 * i; wih[ii] = Wih0[(size_t)jbase * 128 + ii]; }
    if (tid < 128) fcbl[tid] = fcb[tid];
    __syncthreads();
    if (tid < 12) {
      float s = bih0[jbase + tid];
      for (int c = 0; c < 128; ++c) s += wih[tid * 128 + c] * fcbl[c];
      b0f[jbase + tid] = s;
    }
    for (int kt = 0; kt < 16; ++kt) {
      __syncthreads();
      for (int i = 0; i < 32; ++i) {
        int ii = tid + 256 * i; int c = ii >> 6, x = ii & 63;
        fcwt[ii] = fcW[(size_t)c * 1024 + kt * 64 + x];
      }
      __syncthreads();
      int x = tid & 63, jg = tid >> 6;
      for (int jj = 0; jj < 3; ++jj) {
        int j = jg * 3 + jj;
        float s = 0.f;
#pragma unroll 16
        for (int c = 0; c < 128; ++c) s += wih[j * 128 + c] * fcwt[c * 64 + x];
        w0fb[(size_t)(jbase + j) * 1024 + kt * 64 + x] = (bf16_t)s;
      }
    }
  }
  barrier_heavy();   // one-time wbl2/inv; everything after is LLC-direct

  // hoisted per-group biases (read-only after P0)
  float brM = 0.f, bzM = 0.f, bnM = 0.f, br0 = 0.f, bz0 = 0.f, bn0 = 0.f, fcbr = 0.f;
  if (gid == 0) {
    brM = b0f[col]; bzM = b0f[1024 + col]; bnM = b0f[2048 + col];
    br0 = bih0[col]; bz0 = bih0[1024 + col]; bn0 = bih0[2048 + col];
  } else if (gid == 1) {
    brM = bhh0[col]; bzM = bhh0[1024 + col]; bnM = bhh0[2048 + col];
    if (lid < 8) fcbr = fcb[col];
  } else if (gid == 2) {
    brM = bih1[col]; bzM = bih1[1024 + col]; bnM = bih1[2048 + col];
  } else {
    brM = bhh1[col]; bzM = bhh1[1024 + col]; bnM = bhh1[2048 + col];
  }

  // ================= P1: stage LDS weights (persistent) =================
  {
    if (gid == 0) {
      for (int i = 0; i < 24; ++i) {              // W0f slice (bf16 src)
        int cc = tid + 256 * i;
        int w = cc >> 7, x = cc & 127;
        int g = w >> 4, r = w & 15;
        size_t grow = (size_t)g * 1024 + lid * 16 + r;
        bf8 v = *(const bf8*)(w0fb + grow * 1024 + x * 8);
        *(bf8*)(smem + w * 2048 + ((x ^ (w & 7)) * 16)) = v;
      }
      for (int i = 0; i < 3; ++i) {               // W_ih0 slice (K=128, t=0 path)
        int cc = tid + 256 * i;
        int w = cc >> 4, x = cc & 15;
        int g = w >> 4, r = w & 15;
        size_t grow = (size_t)g * 1024 + lid * 16 + r;
        const float* src = Wih0 + grow * 128 + x * 8;
        bf8 v;
#pragma unroll
        for (int e = 0; e < 8; ++e) v[e] = (bf16_t)src[e];
        *(bf8*)(smem + LDS_EXTRA + w * 256 + ((x ^ (w & 7)) * 16)) = v;
      }
    } else {
      const float* Wsrc = (gid == 1) ? Whh0 : (gid == 2) ? Wih1 : Whh1;
      for (int i = 0; i < 24; ++i) {
        int cc = tid + 256 * i;
        int w = cc >> 7, x = cc & 127;
        int g = w >> 4, r = w & 15;
        size_t grow = (size_t)g * 1024 + lid * 16 + r;
        const float* src = Wsrc + grow * 1024 + x * 8;
        bf8 v;
#pragma unroll
        for (int e = 0; e < 8; ++e) v[e] = (bf16_t)src[e];
        *(bf8*)(smem + w * 2048 + ((x ^ (w & 7)) * 16)) = v;
      }
      if (gid == 1 && lid < 8) {                  // fcW slice for y-GEMM
        for (int i = 0; i < 8; ++i) {
          int cc = tid + 256 * i;
          int w = cc >> 7, x = cc & 127;
          const float* src = fcW + (size_t)(lid * 16 + w) * 1024 + x * 8;
          bf8 v;
#pragma unroll
          for (int e = 0; e < 8; ++e) v[e] = (bf16_t)src[e];
          *(bf8*)(smem + LDS_EXTRA + w * 2048 + ((x ^ (w & 7)) * 16)) = v;
        }
      }
    }
    if (gid == 1) {   // gh0 for t=0 (A = initial h0); sets flgB1 = 1
      __syncthreads();
      f4 c0 = {0.f,0.f,0.f,0.f}, c1 = {0.f,0.f,0.f,0.f}, c2 = {0.f,0.f,0.f,0.f};
      gemm3<32, 2048>(h0b, (const char*)smem, lane, wv, c0, c1, c2);
      gh_store_soa(gh0w, lid, wv, lane, c0, c1, c2, brM, bzM, bnM);
      signal_flag(flgB1, 1);
    }
  }

  // ============ main loop: 256 steps, block-granular point-to-point flags ============
  // flag values after step t: A0/A3/B2 = t+1; B1 = t+2 (P1 set it to 1).
  for (int t = 0; t < 256; ++t) {
    const bf16_t* h1prev = h1b + ((t + 1) & 1) * 65536;

    if (gid == 0) {
      if (t == 0) wait1(flgB1, 1);
      else        wait2(flgB1, (unsigned)(t + 1), flgB2, (unsigned)t);
      i4 r0, r1, r2;
      gh_issue(gh0w, lid, wv, lane, r0, r1, r2);      // RTT drains with gemm's loads
      f4 c0 = {0.f,0.f,0.f,0.f}, c1 = {0.f,0.f,0.f,0.f}, c2 = {0.f,0.f,0.f,0.f};
      if (t == 0) {
        gemm3<4, 256>(x0b, (const char*)smem + LDS_EXTRA, lane, wv, c0, c1, c2);
        gru_apply(c0, c1, c2, __builtin_bit_cast(f4, r0), __builtin_bit_cast(f4, r1),
                  __builtin_bit_cast(f4, r2), br0, bz0, bn0, hreg, h0b, hoff, lo);
      } else {
        gemm3<32, 2048>(h1prev, (const char*)smem, lane, wv, c0, c1, c2);
        gru_apply(c0, c1, c2, __builtin_bit_cast(f4, r0), __builtin_bit_cast(f4, r1),
                  __builtin_bit_cast(f4, r2), brM, bzM, bnM, hreg, h0b, hoff, lo);
      }
      signal_flag(flgA0, (unsigned)(t + 1));
    } else if (gid == 3) {
      if (t > 0) wait1(flgB2, (unsigned)t);           // h1[t-1] ready; gh1w[t-1] consumed
      f4 c0 = {0.f,0.f,0.f,0.f}, c1 = {0.f,0.f,0.f,0.f}, c2 = {0.f,0.f,0.f,0.f};
      gemm3<32, 2048>(h1prev, (const char*)smem, lane, wv, c0, c1, c2);
      gh_store_soa(gh1w, lid, wv, lane, c0, c1, c2, brM, bzM, bnM);
      signal_flag(flgA3, (unsigned)(t + 1));
    } else if (gid == 1) {
      if (lid < 8 && t > 0) {                         // y_{t-1}: off critical path
        wait1(flgB2, (unsigned)t);
        f4 y = gemm1(h1prev, (const char*)smem + LDS_EXTRA, lane, wv);
#pragma unroll
        for (int q = 0; q < 4; ++q) {
          int row = wv * 16 + hi * 4 + q;
          out[(size_t)row * 32768 + (size_t)col * 256 + (t - 1)] = y[q] + fcbr;
        }
      }
      wait1(flgA0, (unsigned)(t + 1));                // h0[t] ready
      if (t < 255) {
        f4 c0 = {0.f,0.f,0.f,0.f}, c1 = {0.f,0.f,0.f,0.f}, c2 = {0.f,0.f,0.f,0.f};
        gemm3<32, 2048>(h0b, (const char*)smem, lane, wv, c0, c1, c2);
        gh_store_soa(gh0w, lid, wv, lane, c0, c1, c2, brM, bzM, bnM);
      }
      signal_flag(flgB1, (unsigned)(t + 2));
    } else { // gid == 2
      wait2(flgA0, (unsigned)(t + 1), flgA3, (unsigned)(t + 1));
      i4 r0, r1, r2;
      gh_issue(gh1w, lid, wv, lane, r0, r1, r2);      // RTT drains with gemm's loads
      f4 c0 = {0.f,0.f,0.f,0.f}, c1 = {0.f,0.f,0.f,0.f}, c2 = {0.f,0.f,0.f,0.f};
      gemm3<32, 2048>(h0b, (const char*)smem, lane, wv, c0, c1, c2);
      gru_apply(c0, c1, c2, __builtin_bit_cast(f4, r0), __builtin_bit_cast(f4, r1),
                __builtin_bit_cast(f4, r2), brM, bzM, bnM, hreg,
                h1b + (t & 1) * 65536, hoff, lo);
      signal_flag(flgB2, (unsigned)(t + 1));
    }
  }

  // ---- epilogue: y_255 ----
  if (gid == 1 && lid < 8) {
    wait1(flgB2, 256u);
    const bf16_t* h1last = h1b + 65536;   // slot 255&1 = 1
    f4 y = gemm1(h1last, (const char*)smem + LDS_EXTRA, lane, wv);
#pragma unroll
    for (int q = 0; q < 4; ++q) {
      int row = wv * 16 + hi * 4 + q;
      out[(size_t)row * 32768 + (size_t)col * 256 + 255] = y[q] + fcbr;
    }
  }
}

extern "C" void kernel_launch(void* const* d_in, const int* in_sizes, int n_in,
                              void* d_out, int out_size, void* d_ws, size_t ws_size,
                              hipStream_t stream)
{
  const float* hidden = (const float*)d_in[0];
  const float* frame0 = (const float*)d_in[1];
  const float* Wih0 = (const float*)d_in[2];
  const float* Whh0 = (const float*)d_in[3];
  const float* bih0 = (const float*)d_in[4];
  const float* bhh0 = (const float*)d_in[5];
  const float* Wih1 = (const float*)d_in[6];
  const float* Whh1 = (const float*)d_in[7];
  const float* bih1 = (const float*)d_in[8];
  const float* bhh1 = (const float*)d_in[9];
  const float* fcW  = (const float*)d_in[10];
  const float* fcb  = (const float*)d_in[11];
  float* out = (float*)d_out;
  char*  ws  = (char*)d_ws;

  hipMemsetAsync(ws, 0, 8192, stream);  // zero heavy flags + group flags

  hipFuncSetAttribute((const void*)rnn_persist,
                      hipFuncAttributeMaxDynamicSharedMemorySize, LDS_SIZE);

  void* args[] = { (void*)&hidden, (void*)&frame0, (void*)&Wih0, (void*)&Whh0,
                   (void*)&bih0, (void*)&bhh0, (void*)&Wih1, (void*)&Whh1,
                   (void*)&bih1, (void*)&bhh1, (void*)&fcW, (void*)&fcb,
                   (void*)&out, (void*)&ws };
  hipError_t err = hipLaunchCooperativeKernel((const void*)rnn_persist,
                                              dim3(256), dim3(256), args, LDS_SIZE, stream);
  if (err != hipSuccess) {
    // co-residency is guaranteed anyway: 256 blocks, 1 block/CU (128KB LDS), 256 CUs
    rnn_persist<<<dim3(256), dim3(256), LDS_SIZE, stream>>>(
        hidden, frame0, Wih0, Whh0, bih0, bhh0, Wih1, Whh1, bih1, bhh1, fcW, fcb, out, ws);
  }
}

// Round 14
// 4117.767 us; speedup vs baseline: 1.2711x; 1.0100x over previous
//
#include <hip/hip_runtime.h>
#include <hip/hip_bf16.h>

// SeqDecoderRNN: 2-layer GRU decoder, B=64 H=1024 C=128 T=256.
// Persistent cooperative kernel: 256 blocks x 256 threads, weights LDS-resident.
// Groups of 64 blocks: G0=gi0(+h0 elementwise), G1=gh0 (+y GEMM on 8 blocks),
// G2=gi1(+h1 elementwise), G3=gh1.
// Sync: point-to-point counters (no grid barrier in main loop).
// All cross-block data via relaxed agent-scope atomics (LLC-direct) —
// COMPILER-VISIBLE atomics only: the compiler inserts waitcnt before every
// use INCLUDING register-allocator spills. (r9-r13 lesson: inline-asm loads
// whose dests live across long ranges get spilled by RA before their waitcnt
// -> timing-dependent garbage. Rule #18 generalized.)
// h mirrors stored FRAGMENT-MAJOR: [rt][ks][lane][8] so a wave's A-fragment
// load is 1KB contiguous -> fully-consumed 64B LLC lines.
// sched_barrier(0) fences pin program order around sync (load-bearing).

typedef __bf16 bf16_t;
typedef __bf16 bf8 __attribute__((ext_vector_type(8)));
typedef float  f4  __attribute__((ext_vector_type(4)));
typedef unsigned long long u64;
typedef u64 u64x2 __attribute__((ext_vector_type(2)));

static constexpr unsigned O_FLAGS = 0;                    // 256 u32 heavy-barrier flags
static constexpr unsigned O_CNT   = 1024;                 // 4 counters, 256B apart
static constexpr unsigned O_B0F   = 4096;                 // 3072 f32
static constexpr unsigned O_X0    = O_B0F + 12288;        // 64x128 bf16 (frag-major)
static constexpr unsigned O_H0B   = O_X0  + 16384;        // 64x1024 bf16 (frag-major)
static constexpr unsigned O_H1B   = O_H0B + 131072;       // 2 x 64x1024 bf16 ring (frag-major)
static constexpr unsigned O_GH0   = O_H1B + 262144;       // 64x3072 f32
static constexpr unsigned O_GH1   = O_GH0 + 786432;       // 64x3072 f32
static constexpr unsigned O_W0F   = O_GH1 + 786432;       // 3072x1024 bf16 (W_ih0 @ fc_W)

#define LDS_EXTRA 98304
#define LDS_SIZE  131072

__device__ __forceinline__ void sfence() { __builtin_amdgcn_sched_barrier(0); }

__device__ __forceinline__ float sigmoidf_(float x) { return 1.f / (1.f + __expf(-x)); }
__device__ __forceinline__ float tanhf_(float x) {
  float e = __expf(-2.f * fabsf(x));
  float t = (1.f - e) / (1.f + e);
  return x < 0.f ? -t : t;
}

// ---- LLC-direct (agent-scope relaxed atomic) access helpers ----
__device__ __forceinline__ u64 llc_ld64(const void* p) {
  return __hip_atomic_load((u64*)p, __ATOMIC_RELAXED, __HIP_MEMORY_SCOPE_AGENT);
}
__device__ __forceinline__ float llc_ldf(const float* p) {
  return __hip_atomic_load((float*)p, __ATOMIC_RELAXED, __HIP_MEMORY_SCOPE_AGENT);
}
__device__ __forceinline__ void llc_stf(float* p, float v) {
  __hip_atomic_store(p, v, __ATOMIC_RELAXED, __HIP_MEMORY_SCOPE_AGENT);
}
__device__ __forceinline__ void llc_st32(unsigned* p, unsigned v) {
  __hip_atomic_store(p, v, __ATOMIC_RELAXED, __HIP_MEMORY_SCOPE_AGENT);
}

// frag-major element index for a 64 x (NKS*32) matrix:
//   f(row,col) = ((row>>4)*NKS + (col>>5))*512 + (((col>>3)&3)*16 + (row&15))*8 + (col&7)

// 3-tile (r,z,n gates) GEMM: 16 rows x 48 cols per wave, K = NKS*32.
// A: frag-major bf16, LLC-direct, 16-fragment-deep prefetch (contiguous 1KB/frag/wave).
// B: LDS, XOR-swizzled, register double-buffered.
template<int NKS, int RS>
__device__ __forceinline__ void gemm3(const bf16_t* __restrict__ Afm,
                                      const char* lds, int lane, int rt,
                                      f4& c0, f4& c1, f4& c2)
{
  const int lo = lane & 15, hi = lane >> 4;
  const bf16_t* ap = Afm + (size_t)rt * (NKS * 512) + lane * 8;
  const int sw = lo & 7;
  const char* l0 = lds + lo * RS;
  const char* l1 = lds + (16 + lo) * RS;
  const char* l2 = lds + (32 + lo) * RS;
  u64 ab0[16], ab1[16];
#pragma unroll
  for (int p = 0; p < 16; ++p) {
    if (p < NKS) { ab0[p] = llc_ld64(ap + p * 512); ab1[p] = llc_ld64(ap + p * 512 + 4); }
  }
  int xo0 = (hi ^ sw) * 16;
  bf8 b0 = *(const bf8*)(l0 + xo0);
  bf8 b1 = *(const bf8*)(l1 + xo0);
  bf8 b2 = *(const bf8*)(l2 + xo0);
#pragma unroll
  for (int ks = 0; ks < NKS; ++ks) {
    bf8 nb0, nb1, nb2;
    if (ks + 1 < NKS) {
      const int nxo = (((ks + 1) * 4 + hi) ^ sw) * 16;
      nb0 = *(const bf8*)(l0 + nxo);
      nb1 = *(const bf8*)(l1 + nxo);
      nb2 = *(const bf8*)(l2 + nxo);
    }
    u64x2 tt; tt.x = ab0[ks % 16]; tt.y = ab1[ks % 16];
    bf8 a = __builtin_bit_cast(bf8, tt);
    if (ks + 16 < NKS) {
      ab0[ks % 16] = llc_ld64(ap + (ks + 16) * 512);
      ab1[ks % 16] = llc_ld64(ap + (ks + 16) * 512 + 4);
    }
    c0 = __builtin_amdgcn_mfma_f32_16x16x32_bf16(a, b0, c0, 0, 0, 0);
    c1 = __builtin_amdgcn_mfma_f32_16x16x32_bf16(a, b1, c1, 0, 0, 0);
    c2 = __builtin_amdgcn_mfma_f32_16x16x32_bf16(a, b2, c2, 0, 0, 0);
    b0 = nb0; b1 = nb1; b2 = nb2;
  }
}

// single-tile GEMM (y = h1 @ fcW^T slice): 16 rows x 16 cols per wave, K=1024.
__device__ __forceinline__ f4 gemm1(const bf16_t* __restrict__ Afm,
                                    const char* lds, int lane, int rt)
{
  const int lo = lane & 15, hi = lane >> 4;
  const bf16_t* ap = Afm + (size_t)rt * 16384 + lane * 8;
  const int sw = lo & 7;
  const char* lb = lds + lo * 2048;
  f4 acc = {0.f, 0.f, 0.f, 0.f};
  u64 ab0[16], ab1[16];
#pragma unroll
  for (int p = 0; p < 16; ++p) {
    ab0[p] = llc_ld64(ap + p * 512); ab1[p] = llc_ld64(ap + p * 512 + 4);
  }
  bf8 b = *(const bf8*)(lb + (hi ^ sw) * 16);
#pragma unroll
  for (int ks = 0; ks < 32; ++ks) {
    bf8 nb;
    if (ks + 1 < 32) nb = *(const bf8*)(lb + ((((ks + 1) * 4 + hi) ^ sw) * 16));
    u64x2 tt; tt.x = ab0[ks % 16]; tt.y = ab1[ks % 16];
    bf8 a = __builtin_bit_cast(bf8, tt);
    if (ks + 16 < 32) {
      ab0[ks % 16] = llc_ld64(ap + (ks + 16) * 512);
      ab1[ks % 16] = llc_ld64(ap + (ks + 16) * 512 + 4);
    }
    acc = __builtin_amdgcn_mfma_f32_16x16x32_bf16(a, b, acc, 0, 0, 0);
    b = nb;
  }
  return acc;
}

__device__ __forceinline__ void gh_store(f4 c0, f4 c1, f4 c2, float* __restrict__ dst,
                                         float br, float bz, float bn, int wv, int hi, int col)
{
#pragma unroll
  for (int q = 0; q < 4; ++q) {
    int row = wv * 16 + hi * 4 + q;
    size_t gb = (size_t)row * 3072 + col;
    llc_stf(dst + gb,        c0[q] + br);
    llc_stf(dst + gb + 1024, c1[q] + bz);
    llc_stf(dst + gb + 2048, c2[q] + bn);
  }
}

__device__ __forceinline__ void gh_prefetch(const float* __restrict__ ghw,
                                            int wv, int hi, int col,
                                            f4& g0, f4& g1, f4& g2)
{
#pragma unroll
  for (int q = 0; q < 4; ++q) {
    size_t gb = (size_t)(wv * 16 + hi * 4 + q) * 3072 + col;
    g0[q] = llc_ldf(ghw + gb);
    g1[q] = llc_ldf(ghw + gb + 1024);
    g2[q] = llc_ldf(ghw + gb + 2048);
  }
}

// GRU elementwise; f32 master state in registers; bf16 mirror published to
// frag-major layout via lane-pair-packed u32 LLC stores.
// hoff = frag offset (elements) for this thread's q=0 element; q-th at +q*8.
__device__ __forceinline__ void gru_apply(f4 c0, f4 c1, f4 c2, f4 g0, f4 g1, f4 g2,
                                          float br, float bz, float bn,
                                          float hreg[4], bf16_t* __restrict__ hb,
                                          int hoff, int lo)
{
#pragma unroll
  for (int q = 0; q < 4; ++q) {
    float r = sigmoidf_(c0[q] + br + g0[q]);
    float z = sigmoidf_(c1[q] + bz + g1[q]);
    float n = tanhf_  (c2[q] + bn + r * g2[q]);
    float hv = (1.f - z) * n + z * hreg[q];
    hreg[q] = hv;
    unsigned my = (unsigned)__builtin_bit_cast(unsigned short, (bf16_t)hv);
    unsigned ot = __shfl_xor(my, 1, 64);
    if ((lo & 1) == 0)
      llc_st32((unsigned*)(hb + hoff + q * 8), my | (ot << 16));
  }
}

__global__ void __launch_bounds__(256, 1)
rnn_persist(const float* __restrict__ hidden, const float* __restrict__ frame0,
            const float* __restrict__ Wih0, const float* __restrict__ Whh0,
            const float* __restrict__ bih0, const float* __restrict__ bhh0,
            const float* __restrict__ Wih1, const float* __restrict__ Whh1,
            const float* __restrict__ bih1, const float* __restrict__ bhh1,
            const float* __restrict__ fcW, const float* __restrict__ fcb,
            float* __restrict__ out, char* __restrict__ ws)
{
  extern __shared__ char smem[];
  const int tid = threadIdx.x;
  const int bid = blockIdx.x;
  const int gid = bid >> 6;     // 0:gi0  1:gh0(+y)  2:gi1  3:gh1
  const int lid = bid & 63;     // h-columns [lid*16, lid*16+16)
  const int lane = tid & 63;
  const int wv = tid >> 6;      // wave = row-tile (16 batch rows)
  const int lo = lane & 15, hi = lane >> 4;

  unsigned* flags = (unsigned*)(ws + O_FLAGS);
  unsigned* cntA0 = (unsigned*)(ws + O_CNT);          // G0 phase-A completions
  unsigned* cntA3 = (unsigned*)(ws + O_CNT + 256);    // G3 phase-A completions
  unsigned* cntB1 = (unsigned*)(ws + O_CNT + 512);    // G1 gh0 completions (incl. P1)
  unsigned* cntB2 = (unsigned*)(ws + O_CNT + 768);    // G2 phase-B completions
  float*  b0f  = (float*)(ws + O_B0F);
  bf16_t* x0b  = (bf16_t*)(ws + O_X0);
  bf16_t* h0b  = (bf16_t*)(ws + O_H0B);
  bf16_t* h1b  = (bf16_t*)(ws + O_H1B);   // [2][65536] frag-major ring
  float*  gh0w = (float*)(ws + O_GH0);
  float*  gh1w = (float*)(ws + O_GH1);
  bf16_t* w0fb = (bf16_t*)(ws + O_W0F);

  // ---- point-to-point sync primitives ----
  // sched_barrier(0) pins program order: hipcc may hoist loads past inline-asm
  // waits / s_barrier (rule #18); hardware itself is in-order per wave.
  auto signal_cnt = [&](unsigned* cnt) {
    sfence();
    asm volatile("s_waitcnt vmcnt(0)" ::: "memory");   // all LLC stores ack'd
    __syncthreads();                                    // all waves of block done
    if (tid == 0)
      (void)__hip_atomic_fetch_add(cnt, 1u, __ATOMIC_RELAXED, __HIP_MEMORY_SCOPE_AGENT);
  };
  auto wait_cnt = [&](unsigned* cnt, unsigned target) {
    if (tid == 0) {
      while (__hip_atomic_load(cnt, __ATOMIC_RELAXED, __HIP_MEMORY_SCOPE_AGENT) < target) {}
    }
    __syncthreads();
    sfence();   // nothing below may be scheduled above this point
  };
  // ---- one-time heavy barrier after P0 (plain-store-initialized data) ----
  auto barrier_heavy = [&]() {
    __syncthreads();
    if (tid == 0)
      __hip_atomic_store(&flags[bid], 1u, __ATOMIC_RELEASE, __HIP_MEMORY_SCOPE_AGENT);
    if (tid < 64) {
      const u64* fp = (const u64*)(flags) + tid * 2;
      for (;;) {
        u64 a = llc_ld64(fp), b = llc_ld64(fp + 1);
        if ((unsigned)a && (unsigned)(a >> 32) && (unsigned)b && (unsigned)(b >> 32)) break;
        __builtin_amdgcn_s_sleep(1);
      }
    }
    __syncthreads();
    __builtin_amdgcn_fence(__ATOMIC_ACQUIRE, "agent");
    sfence();
  };

  const int col = lid * 16 + lo;
  // frag-major write offset for gru_apply (this thread's q=0 element):
  const int hoff = (wv * 32 + (lid >> 1)) * 512
                 + ((((lid & 1) << 1) + (lo >> 3)) * 16 + hi * 4) * 8 + (lo & 7);
  float hreg[4];

  // ================= P0: distributed prep =================
  {
    // bf16 mirrors of hidden, FRAG-MAJOR (h1 init into ring slot 1); plain stores
#pragma unroll
    for (int it = 0; it < 2; ++it) {
      int idx = bid * 512 + it * 256 + tid;   // 0..131071
      float v = hidden[idx];
      int layer = idx >> 16, rc = idx & 65535;
      int row = rc >> 10, c = rc & 1023;
      int f = ((row >> 4) * 32 + (c >> 5)) * 512 + (((c >> 3) & 3) * 16 + (row & 15)) * 8 + (c & 7);
      if (layer == 0) h0b[f] = (bf16_t)v;
      else            h1b[65536 + f] = (bf16_t)v;
    }
    if (gid == 0 || gid == 2) {
#pragma unroll
      for (int q = 0; q < 4; ++q) {
        int row = wv * 16 + hi * 4 + q;
        hreg[q] = hidden[(gid == 0 ? 0 : 65536) + (size_t)row * 1024 + col];
      }
    }
    if (bid < 32) {   // frame0 -> frag-major 64x128
      int idx = bid * 256 + tid;   // 0..8191
      int row = idx >> 7, c = idx & 127;
      int f = ((row >> 4) * 4 + (c >> 5)) * 512 + (((c >> 3) & 3) * 16 + (row & 15)) * 8 + (c & 7);
      x0b[f] = (bf16_t)frame0[idx];
    }

    // W0f = W_ih0 @ fc_W (rows [bid*12, bid*12+12)) and b0f = b_ih0 + W_ih0 @ fc_b
    float* wih  = (float*)smem;      // 12*128
    float* fcbl = wih + 1536;        // 128
    float* fcwt = fcbl + 128;        // 128*64
    const int jbase = bid * 12;
    for (int i = 0; i < 6; ++i) { int ii = tid + 256 * i; wih[ii] = Wih0[(size_t)jbase * 128 + ii]; }
    if (tid < 128) fcbl[tid] = fcb[tid];
    __syncthreads();
    if (tid < 12) {
      float s = bih0[jbase + tid];
      for (int c = 0; c < 128; ++c) s += wih[tid * 128 + c] * fcbl[c];
      b0f[jbase + tid] = s;
    }
    for (int kt = 0; kt < 16; ++kt) {
      __syncthreads();
      for (int i = 0; i < 32; ++i) {
        int ii = tid + 256 * i; int c = ii >> 6, x = ii & 63;
        fcwt[ii] = fcW[(size_t)c * 1024 + kt * 64 + x];
      }
      __syncthreads();
      int x = tid & 63, jg = tid >> 6;
      for (int jj = 0; jj < 3; ++jj) {
        int j = jg * 3 + jj;
        float s = 0.f;
#pragma unroll 16
        for (int c = 0; c < 128; ++c) s += wih[j * 128 + c] * fcwt[c * 64 + x];
        w0fb[(size_t)(jbase + j) * 1024 + kt * 64 + x] = (bf16_t)s;
      }
    }
  }
  barrier_heavy();   // one-time wbl2/inv; everything after is LLC-direct

  // hoisted per-group biases (read-only after P0)
  float brM = 0.f, bzM = 0.f, bnM = 0.f, br0 = 0.f, bz0 = 0.f, bn0 = 0.f, fcbr = 0.f;
  if (gid == 0) {
    brM = b0f[col]; bzM = b0f[1024 + col]; bnM = b0f[2048 + col];
    br0 = bih0[col]; bz0 = bih0[1024 + col]; bn0 = bih0[2048 + col];
  } else if (gid == 1) {
    brM = bhh0[col]; bzM = bhh0[1024 + col]; bnM = bhh0[2048 + col];
    if (lid < 8) fcbr = fcb[col];
  } else if (gid == 2) {
    brM = bih1[col]; bzM = bih1[1024 + col]; bnM = bih1[2048 + col];
  } else {
    brM = bhh1[col]; bzM = bhh1[1024 + col]; bnM = bhh1[2048 + col];
  }

  // ================= P1: stage LDS weights (persistent) =================
  {
    if (gid == 0) {
      for (int i = 0; i < 24; ++i) {              // W0f slice (bf16 src)
        int cc = tid + 256 * i;
        int w = cc >> 7, x = cc & 127;
        int g = w >> 4, r = w & 15;
        size_t grow = (size_t)g * 1024 + lid * 16 + r;
        bf8 v = *(const bf8*)(w0fb + grow * 1024 + x * 8);
        *(bf8*)(smem + w * 2048 + ((x ^ (w & 7)) * 16)) = v;
      }
      for (int i = 0; i < 3; ++i) {               // W_ih0 slice (K=128, t=0 path)
        int cc = tid + 256 * i;
        int w = cc >> 4, x = cc & 15;
        int g = w >> 4, r = w & 15;
        size_t grow = (size_t)g * 1024 + lid * 16 + r;
        const float* src = Wih0 + grow * 128 + x * 8;
        bf8 v;
#pragma unroll
        for (int e = 0; e < 8; ++e) v[e] = (bf16_t)src[e];
        *(bf8*)(smem + LDS_EXTRA + w * 256 + ((x ^ (w & 7)) * 16)) = v;
      }
    } else {
      const float* Wsrc = (gid == 1) ? Whh0 : (gid == 2) ? Wih1 : Whh1;
      for (int i = 0; i < 24; ++i) {
        int cc = tid + 256 * i;
        int w = cc >> 7, x = cc & 127;
        int g = w >> 4, r = w & 15;
        size_t grow = (size_t)g * 1024 + lid * 16 + r;
        const float* src = Wsrc + grow * 1024 + x * 8;
        bf8 v;
#pragma unroll
        for (int e = 0; e < 8; ++e) v[e] = (bf16_t)src[e];
        *(bf8*)(smem + w * 2048 + ((x ^ (w & 7)) * 16)) = v;
      }
      if (gid == 1 && lid < 8) {                  // fcW slice for y-GEMM
        for (int i = 0; i < 8; ++i) {
          int cc = tid + 256 * i;
          int w = cc >> 7, x = cc & 127;
          const float* src = fcW + (size_t)(lid * 16 + w) * 1024 + x * 8;
          bf8 v;
#pragma unroll
          for (int e = 0; e < 8; ++e) v[e] = (bf16_t)src[e];
          *(bf8*)(smem + LDS_EXTRA + w * 2048 + ((x ^ (w & 7)) * 16)) = v;
        }
      }
    }
    if (gid == 1) {   // gh0 for t=0 (A = initial h0); bumps cntB1 to 64
      __syncthreads();
      f4 c0 = {0.f,0.f,0.f,0.f}, c1 = {0.f,0.f,0.f,0.f}, c2 = {0.f,0.f,0.f,0.f};
      gemm3<32, 2048>(h0b, (const char*)smem, lane, wv, c0, c1, c2);
      gh_store(c0, c1, c2, gh0w, brM, bzM, bnM, wv, hi, col);
      signal_cnt(cntB1);
    }
  }
  // no other barrier: main-loop waits cover every cross-group dependency

  // ================= main loop: 256 steps, point-to-point sync =================
  // counter values: cntA0/cntA3/cntB2 after step t = 64*(t+1);
  //                 cntB1 after P1 = 64, after step-t phase B = 64*(t+2).
  for (int t = 0; t < 256; ++t) {
    const unsigned tgt = 64u * (t + 1);
    const bf16_t* h1prev = h1b + ((t + 1) & 1) * 65536;

    if (gid == 0) {
      wait_cnt(cntB1, tgt);
      if (t > 0) wait_cnt(cntB2, tgt - 64);
      f4 g0, g1, g2;
      gh_prefetch(gh0w, wv, hi, col, g0, g1, g2);
      f4 c0 = {0.f,0.f,0.f,0.f}, c1 = {0.f,0.f,0.f,0.f}, c2 = {0.f,0.f,0.f,0.f};
      if (t == 0) {
        gemm3<4, 256>(x0b, (const char*)smem + LDS_EXTRA, lane, wv, c0, c1, c2);
        gru_apply(c0, c1, c2, g0, g1, g2, br0, bz0, bn0, hreg, h0b, hoff, lo);
      } else {
        gemm3<32, 2048>(h1prev, (const char*)smem, lane, wv, c0, c1, c2);
        gru_apply(c0, c1, c2, g0, g1, g2, brM, bzM, bnM, hreg, h0b, hoff, lo);
      }
      signal_cnt(cntA0);
    } else if (gid == 3) {
      if (t > 0) wait_cnt(cntB2, tgt - 64);        // h1[t-1] ready, gh1w[t-1] consumed
      f4 c0 = {0.f,0.f,0.f,0.f}, c1 = {0.f,0.f,0.f,0.f}, c2 = {0.f,0.f,0.f,0.f};
      gemm3<32, 2048>(h1prev, (const char*)smem, lane, wv, c0, c1, c2);
      gh_store(c0, c1, c2, gh1w, brM, bzM, bnM, wv, hi, col);
      signal_cnt(cntA3);
    } else if (gid == 1) {
      if (lid < 8 && t > 0) {                      // y_{t-1}: off critical path
        wait_cnt(cntB2, tgt - 64);
        f4 y = gemm1(h1prev, (const char*)smem + LDS_EXTRA, lane, wv);
#pragma unroll
        for (int q = 0; q < 4; ++q) {
          int row = wv * 16 + hi * 4 + q;
          out[(size_t)row * 32768 + (size_t)col * 256 + (t - 1)] = y[q] + fcbr;
        }
      }
      wait_cnt(cntA0, tgt);                        // h0[t] ready
      if (t < 255) {
        f4 c0 = {0.f,0.f,0.f,0.f}, c1 = {0.f,0.f,0.f,0.f}, c2 = {0.f,0.f,0.f,0.f};
        gemm3<32, 2048>(h0b, (const char*)smem, lane, wv, c0, c1, c2);
        gh_store(c0, c1, c2, gh0w, brM, bzM, bnM, wv, hi, col);
      }
      signal_cnt(cntB1);
    } else { // gid == 2
      wait_cnt(cntA0, tgt);                        // h0[t]
      wait_cnt(cntA3, tgt);                        // gh1w[t]
      f4 g0, g1, g2;
      gh_prefetch(gh1w, wv, hi, col, g0, g1, g2);
      f4 c0 = {0.f,0.f,0.f,0.f}, c1 = {0.f,0.f,0.f,0.f}, c2 = {0.f,0.f,0.f,0.f};
      gemm3<32, 2048>(h0b, (const char*)smem, lane, wv, c0, c1, c2);
      gru_apply(c0, c1, c2, g0, g1, g2, brM, bzM, bnM, hreg,
                h1b + (t & 1) * 65536, hoff, lo);
      signal_cnt(cntB2);
    }
  }

  // ---- epilogue: y_255 ----
  if (gid == 1 && lid < 8) {
    wait_cnt(cntB2, 64u * 256);
    const bf16_t* h1last = h1b + 65536;   // slot 255&1 = 1
    f4 y = gemm1(h1last, (const char*)smem + LDS_EXTRA, lane, wv);
#pragma unroll
    for (int q = 0; q < 4; ++q) {
      int row = wv * 16 + hi * 4 + q;
      out[(size_t)row * 32768 + (size_t)col * 256 + 255] = y[q] + fcbr;
    }
  }
}

extern "C" void kernel_launch(void* const* d_in, const int* in_sizes, int n_in,
                              void* d_out, int out_size, void* d_ws, size_t ws_size,
                              hipStream_t stream)
{
  const float* hidden = (const float*)d_in[0];
  const float* frame0 = (const float*)d_in[1];
  const float* Wih0 = (const float*)d_in[2];
  const float* Whh0 = (const float*)d_in[3];
  const float* bih0 = (const float*)d_in[4];
  const float* bhh0 = (const float*)d_in[5];
  const float* Wih1 = (const float*)d_in[6];
  const float* Whh1 = (const float*)d_in[7];
  const float* bih1 = (const float*)d_in[8];
  const float* bhh1 = (const float*)d_in[9];
  const float* fcW  = (const float*)d_in[10];
  const float* fcb  = (const float*)d_in[11];
  float* out = (float*)d_out;
  char*  ws  = (char*)d_ws;

  hipMemsetAsync(ws, 0, 4096, stream);  // zero flags + counters

  hipFuncSetAttribute((const void*)rnn_persist,
                      hipFuncAttributeMaxDynamicSharedMemorySize, LDS_SIZE);

  void* args[] = { (void*)&hidden, (void*)&frame0, (void*)&Wih0, (void*)&Whh0,
                   (void*)&bih0, (void*)&bhh0, (void*)&Wih1, (void*)&Whh1,
                   (void*)&bih1, (void*)&bhh1, (void*)&fcW, (void*)&fcb,
                   (void*)&out, (void*)&ws };
  hipError_t err = hipLaunchCooperativeKernel((const void*)rnn_persist,
                                              dim3(256), dim3(256), args, LDS_SIZE, stream);
  if (err != hipSuccess) {
    // co-residency is guaranteed anyway: 256 blocks, 1 block/CU (128KB LDS), 256 CUs
    rnn_persist<<<dim3(256), dim3(256), LDS_SIZE, stream>>>(
        hidden, frame0, Wih0, Whh0, bih0, bhh0, Wih1, Whh1, bih1, bhh1, fcW, fcb, out, ws);
  }
}